// Round 2
// baseline (1523.271 us; speedup 1.0000x reference)
//
#include <hip/hip_runtime.h>
#include <hip/hip_bf16.h>
#include <math.h>

#define BB 64
#define TT 512
#define OBSD 115
#define DMD 128
#define DSD 8
#define NLD 3
#define EMBD 16
#define NAD 19
#define H1D 256
#define NTOK (BB*TT)

__device__ __forceinline__ float wsum(float v){
  #pragma unroll
  for (int o = 1; o < 64; o <<= 1) v += __shfl_xor(v, o, 64);
  return v;
}
__device__ __forceinline__ float silu_f(float x){ return x / (1.f + __expf(-x)); }
__device__ __forceinline__ float softplus_f(float x){
  return fmaxf(x, 0.f) + log1pf(__expf(-fabsf(x)));
}

// ---------------- K1: e1 = silu(LN(obs @ enc_w1.T + b1)) ----------------
__global__ __launch_bounds__(256) void k_enc1(
    const float* __restrict__ obs, const float* __restrict__ w1,
    const float* __restrict__ b1, const float* __restrict__ g1,
    const float* __restrict__ bb1, float* __restrict__ e1)
{
  __shared__ float s_obs[8][116];
  __shared__ float s_val[8][256];
  __shared__ float s_mr[8][2];
  const int tok0 = blockIdx.x * 8;
  const int j = threadIdx.x;

  for (int idx = j; idx < 8*OBSD; idx += 256){
    int t = idx / OBSD, k = idx - t*OBSD;
    s_obs[t][k] = obs[(tok0 + t)*OBSD + k];
  }
  __syncthreads();

  float acc[8] = {0.f,0.f,0.f,0.f,0.f,0.f,0.f,0.f};
  const float* wr = w1 + j*OBSD;
  for (int k = 0; k < OBSD; k++){
    float w = wr[k];
    #pragma unroll
    for (int t = 0; t < 8; t++) acc[t] += s_obs[t][k] * w;
  }
  float bias = b1[j];
  #pragma unroll
  for (int t = 0; t < 8; t++) s_val[t][j] = acc[t] + bias;
  __syncthreads();

  int wave = j >> 6, lane = j & 63;
  for (int t = wave*2; t < wave*2 + 2; t++){
    float v0 = s_val[t][lane], v1 = s_val[t][lane+64];
    float v2 = s_val[t][lane+128], v3 = s_val[t][lane+192];
    float m = wsum(v0+v1+v2+v3) * (1.f/256.f);
    float d0=v0-m, d1=v1-m, d2=v2-m, d3=v3-m;
    float var = wsum(d0*d0+d1*d1+d2*d2+d3*d3) * (1.f/256.f);
    float rstd = rsqrtf(var + 1e-5f);
    if (lane == 0){ s_mr[t][0] = m; s_mr[t][1] = rstd; }
  }
  __syncthreads();

  float g = g1[j], bb = bb1[j];
  #pragma unroll
  for (int t = 0; t < 8; t++){
    float v = (s_val[t][j] - s_mr[t][0]) * s_mr[t][1] * g + bb;
    e1[(tok0 + t)*H1D + j] = silu_f(v);
  }
}

// ------- K2: e2 = LN(e1@w2.T+b2); x = silu(LN([e2,emb[pa]]@pw.T+pb)) -------
__global__ __launch_bounds__(128) void k_enc2_proj(
    const float* __restrict__ e1,
    const float* __restrict__ w2, const float* __restrict__ b2,
    const float* __restrict__ g2, const float* __restrict__ bb2,
    const float* __restrict__ emb, const int* __restrict__ pact,
    const float* __restrict__ pw, const float* __restrict__ pb,
    const float* __restrict__ pg, const float* __restrict__ pbb,
    float* __restrict__ X)
{
  __shared__ float s_e1[8][256];
  __shared__ float s_h[8][144];
  __shared__ float s_mr[8][2];
  const int tok0 = blockIdx.x * 8;
  const int j = threadIdx.x;
  int wave = j >> 6, lane = j & 63;

  for (int idx = j; idx < 8*256; idx += 128) ((float*)s_e1)[idx] = e1[tok0*256 + idx];
  for (int idx = j; idx < 8*EMBD; idx += 128){
    int t = idx >> 4, k = idx & 15;
    int a = pact[tok0 + t];
    s_h[t][DMD + k] = emb[a*EMBD + k];
  }
  __syncthreads();

  float acc[8] = {0.f,0.f,0.f,0.f,0.f,0.f,0.f,0.f};
  const float* wr = w2 + j*256;
  for (int k = 0; k < 256; k++){
    float w = wr[k];
    #pragma unroll
    for (int t = 0; t < 8; t++) acc[t] += s_e1[t][k] * w;
  }
  float bias = b2[j];
  __syncthreads();                       // all dots done before overwrite
  #pragma unroll
  for (int t = 0; t < 8; t++) s_e1[t][j] = acc[t] + bias;
  __syncthreads();

  for (int t = wave*4; t < wave*4 + 4; t++){
    float v0 = s_e1[t][lane], v1 = s_e1[t][lane+64];
    float m = wsum(v0+v1) * (1.f/128.f);
    float d0=v0-m, d1=v1-m;
    float var = wsum(d0*d0+d1*d1) * (1.f/128.f);
    float rstd = rsqrtf(var + 1e-5f);
    if (lane == 0){ s_mr[t][0] = m; s_mr[t][1] = rstd; }
  }
  __syncthreads();
  {
    float g = g2[j], bb = bb2[j];
    #pragma unroll
    for (int t = 0; t < 8; t++)
      s_h[t][j] = (s_e1[t][j] - s_mr[t][0]) * s_mr[t][1] * g + bb;
  }
  __syncthreads();

  float a2[8] = {0.f,0.f,0.f,0.f,0.f,0.f,0.f,0.f};
  const float* wr2 = pw + j*(DMD+EMBD);
  for (int k = 0; k < DMD+EMBD; k++){
    float w = wr2[k];
    #pragma unroll
    for (int t = 0; t < 8; t++) a2[t] += s_h[t][k] * w;
  }
  float pbias = pb[j];
  #pragma unroll
  for (int t = 0; t < 8; t++) s_e1[t][j] = a2[t] + pbias;
  __syncthreads();

  for (int t = wave*4; t < wave*4 + 4; t++){
    float v0 = s_e1[t][lane], v1 = s_e1[t][lane+64];
    float m = wsum(v0+v1) * (1.f/128.f);
    float d0=v0-m, d1=v1-m;
    float var = wsum(d0*d0+d1*d1) * (1.f/128.f);
    float rstd = rsqrtf(var + 1e-5f);
    if (lane == 0){ s_mr[t][0] = m; s_mr[t][1] = rstd; }
  }
  __syncthreads();
  {
    float g = pg[j], bb = pbb[j];
    #pragma unroll
    for (int t = 0; t < 8; t++){
      float v = (s_e1[t][j] - s_mr[t][0]) * s_mr[t][1] * g + bb;
      X[(tok0 + t)*DMD + j] = silu_f(v);
    }
  }
}

// ----- K3: per-layer pre: xn=LN(x); xp=xn@wig.T; dt,bt,ct from x_in -----
__global__ __launch_bounds__(256) void k_pre(
    const float* __restrict__ X,
    const float* __restrict__ lng, const float* __restrict__ lnb,
    const float* __restrict__ wig, const float* __restrict__ wdt,
    const float* __restrict__ bdt, const float* __restrict__ wb,
    const float* __restrict__ wc,
    float* __restrict__ XIN, float* __restrict__ Z, float* __restrict__ DT,
    float* __restrict__ BT, float* __restrict__ CT)
{
  __shared__ float s_x[8][128];
  __shared__ float s_xn[8][128];
  __shared__ float s_xin[8][128];
  __shared__ float s_mr[8][2];
  const int tok0 = blockIdx.x * 8;
  const int j = threadIdx.x;
  int wave = j >> 6, lane = j & 63;

  for (int idx = j; idx < 1024; idx += 256) ((float*)s_x)[idx] = X[tok0*128 + idx];
  __syncthreads();

  for (int t = wave*2; t < wave*2 + 2; t++){
    float v0 = s_x[t][lane], v1 = s_x[t][lane+64];
    float m = wsum(v0+v1) * (1.f/128.f);
    float d0=v0-m, d1=v1-m;
    float var = wsum(d0*d0+d1*d1) * (1.f/128.f);
    float rstd = rsqrtf(var + 1e-5f);
    if (lane == 0){ s_mr[t][0] = m; s_mr[t][1] = rstd; }
  }
  __syncthreads();
  for (int idx = j; idx < 1024; idx += 256){
    int t = idx >> 7, c = idx & 127;
    s_xn[t][c] = (s_x[t][c] - s_mr[t][0]) * s_mr[t][1] * lng[c] + lnb[c];
  }
  __syncthreads();

  float acc[8] = {0.f,0.f,0.f,0.f,0.f,0.f,0.f,0.f};
  const float* wr = wig + j*128;
  for (int k = 0; k < 128; k++){
    float w = wr[k];
    #pragma unroll
    for (int t = 0; t < 8; t++) acc[t] += s_xn[t][k] * w;
  }
  if (j < 128){
    #pragma unroll
    for (int t = 0; t < 8; t++){
      s_xin[t][j] = acc[t];
      XIN[(tok0 + t)*128 + j] = acc[t];
    }
  } else {
    int jj = j - 128;
    #pragma unroll
    for (int t = 0; t < 8; t++) Z[(tok0 + t)*128 + jj] = acc[t];
  }
  __syncthreads();

  if (j < 128){
    float a[8] = {0.f,0.f,0.f,0.f,0.f,0.f,0.f,0.f};
    const float* wr2 = wdt + j*128;
    for (int k = 0; k < 128; k++){
      float w = wr2[k];
      #pragma unroll
      for (int t = 0; t < 8; t++) a[t] += s_xin[t][k] * w;
    }
    float bd = bdt[j];
    #pragma unroll
    for (int t = 0; t < 8; t++) DT[(tok0 + t)*128 + j] = softplus_f(a[t] + bd);
  } else {
    int idx = j - 128;            // 0..127
    int half = idx >> 6;          // 0: bt, 1: ct
    int r = idx & 63; int t = r >> 3, s = r & 7;
    const float* wr2 = (half ? wc : wb) + s*128;
    float a = 0.f;
    for (int k = 0; k < 128; k++) a += s_xin[t][k] * wr2[k];
    if (half) CT[(tok0 + t)*8 + s] = a;
    else      BT[(tok0 + t)*8 + s] = a;
  }
}

// ---------------- K4: sequential scan over T ----------------
// Y aliases DT: each (b,d) column is private to one 8-lane group; within the
// lockstep wave, loads of iteration t complete (dependency chain through h/y)
// before lane s==0's store to the same address. No cross-wave sharing.
__global__ __launch_bounds__(256) void k_scan(
    const float* __restrict__ DT, const float* __restrict__ XIN,
    const float* __restrict__ BT, const float* __restrict__ CT,
    const float* __restrict__ h0, const float* __restrict__ alog,
    float* __restrict__ Y)
{
  const int blk = blockIdx.x;
  const int b = blk >> 2, dg = blk & 3;
  const int tid = threadIdx.x;
  const int d_sub = tid >> 3, s = tid & 7;
  const int d = dg*32 + d_sub;

  const float A = -__expf(alog[d*DSD + s]);
  float h = h0[b*(DMD*DSD) + d*DSD + s];

  const float* dtp = DT + (size_t)b*TT*128 + d;
  const float* xip = XIN + (size_t)b*TT*128 + d;
  const float* btp = BT + (size_t)b*TT*8 + s;
  const float* ctp = CT + (size_t)b*TT*8 + s;
  float* yp = Y + (size_t)b*TT*128 + d;

  #pragma unroll 4
  for (int t = 0; t < TT; t++){
    float dt = dtp[t*128];
    float xi = xip[t*128];
    float bt = btp[t*8];
    float ct = ctp[t*8];
    float dA = __expf(dt * A);
    h = dA*h + dt*xi*bt;
    float y = h * ct;
    y += __shfl_xor(y, 1, 64);
    y += __shfl_xor(y, 2, 64);
    y += __shfl_xor(y, 4, 64);
    if (s == 0) yp[t*128] = y;
  }
}

// ------- K5: x += (y*silu(z) + x_in*d) @ w_out.T -------
__global__ __launch_bounds__(128) void k_post(
    float* __restrict__ X,
    const float* __restrict__ Y, const float* __restrict__ Z,
    const float* __restrict__ XIN,
    const float* __restrict__ dpar, const float* __restrict__ wout)
{
  __shared__ float s_ssm[8][128];
  const int tok0 = blockIdx.x * 8;
  const int j = threadIdx.x;

  for (int idx = j; idx < 1024; idx += 128){
    int c = idx & 127;
    float y = Y[tok0*128 + idx], z = Z[tok0*128 + idx], xi = XIN[tok0*128 + idx];
    ((float*)s_ssm)[idx] = y * silu_f(z) + xi * dpar[c];
  }
  __syncthreads();

  float acc[8] = {0.f,0.f,0.f,0.f,0.f,0.f,0.f,0.f};
  const float* wr = wout + j*128;
  for (int k = 0; k < 128; k++){
    float w = wr[k];
    #pragma unroll
    for (int t = 0; t < 8; t++) acc[t] += s_ssm[t][k] * w;
  }
  #pragma unroll
  for (int t = 0; t < 8; t++) X[(tok0 + t)*128 + j] += acc[t];
}

// ------- K6: head: LN(fn); p=silu(LN(x@pw1.T+pb1)); out=p@pw2.T+pb2 -------
__global__ __launch_bounds__(128) void k_head(
    const float* __restrict__ X,
    const float* __restrict__ fng, const float* __restrict__ fnb,
    const float* __restrict__ pw1, const float* __restrict__ pb1,
    const float* __restrict__ pg, const float* __restrict__ pbb,
    const float* __restrict__ pw2, const float* __restrict__ pb2,
    float* __restrict__ out)
{
  __shared__ float s_a[8][128];
  __shared__ float s_n[8][128];
  __shared__ float s_mr[8][2];
  const int tok0 = blockIdx.x * 8;
  const int j = threadIdx.x;
  int wave = j >> 6, lane = j & 63;

  for (int idx = j; idx < 1024; idx += 128) ((float*)s_a)[idx] = X[tok0*128 + idx];
  __syncthreads();

  for (int t = wave*4; t < wave*4 + 4; t++){
    float v0 = s_a[t][lane], v1 = s_a[t][lane+64];
    float m = wsum(v0+v1) * (1.f/128.f);
    float d0=v0-m, d1=v1-m;
    float var = wsum(d0*d0+d1*d1) * (1.f/128.f);
    float rstd = rsqrtf(var + 1e-5f);
    if (lane == 0){ s_mr[t][0] = m; s_mr[t][1] = rstd; }
  }
  __syncthreads();
  {
    float g = fng[j], bb = fnb[j];
    #pragma unroll
    for (int t = 0; t < 8; t++)
      s_n[t][j] = (s_a[t][j] - s_mr[t][0]) * s_mr[t][1] * g + bb;
  }
  __syncthreads();

  float acc[8] = {0.f,0.f,0.f,0.f,0.f,0.f,0.f,0.f};
  const float* wr = pw1 + j*128;
  for (int k = 0; k < 128; k++){
    float w = wr[k];
    #pragma unroll
    for (int t = 0; t < 8; t++) acc[t] += s_n[t][k] * w;
  }
  float b1v = pb1[j];
  __syncthreads();
  #pragma unroll
  for (int t = 0; t < 8; t++) s_a[t][j] = acc[t] + b1v;
  __syncthreads();

  for (int t = wave*4; t < wave*4 + 4; t++){
    float v0 = s_a[t][lane], v1 = s_a[t][lane+64];
    float m = wsum(v0+v1) * (1.f/128.f);
    float d0=v0-m, d1=v1-m;
    float var = wsum(d0*d0+d1*d1) * (1.f/128.f);
    float rstd = rsqrtf(var + 1e-5f);
    if (lane == 0){ s_mr[t][0] = m; s_mr[t][1] = rstd; }
  }
  __syncthreads();
  {
    float g = pg[j], bb = pbb[j];
    #pragma unroll
    for (int t = 0; t < 8; t++)
      s_n[t][j] = silu_f((s_a[t][j] - s_mr[t][0]) * s_mr[t][1] * g + bb);
  }
  __syncthreads();

  for (int idx = j; idx < 8*NAD; idx += 128){
    int t = idx / NAD, o = idx - t*NAD;
    const float* wr2 = pw2 + o*128;
    float a = pb2[o];
    for (int k = 0; k < 128; k++) a += s_n[t][k] * wr2[k];
    out[(tok0 + t)*NAD + o] = a;
  }
}

extern "C" void kernel_launch(void* const* d_in, const int* in_sizes, int n_in,
                              void* d_out, int out_size, void* d_ws, size_t ws_size,
                              hipStream_t stream) {
  const float* obs    = (const float*)d_in[0];
  const float* h0     = (const float*)d_in[1];
  const float* enc_w1 = (const float*)d_in[2];
  const float* enc_b1 = (const float*)d_in[3];
  const float* enc_g1 = (const float*)d_in[4];
  const float* enc_bb1= (const float*)d_in[5];
  const float* enc_w2 = (const float*)d_in[6];
  const float* enc_b2 = (const float*)d_in[7];
  const float* enc_g2 = (const float*)d_in[8];
  const float* enc_bb2= (const float*)d_in[9];
  const float* emb    = (const float*)d_in[10];
  const float* proj_w = (const float*)d_in[11];
  const float* proj_b = (const float*)d_in[12];
  const float* proj_g = (const float*)d_in[13];
  const float* proj_bb= (const float*)d_in[14];
  const float* m_ln_g = (const float*)d_in[15];
  const float* m_ln_b = (const float*)d_in[16];
  const float* m_w_ig = (const float*)d_in[17];
  const float* m_w_dt = (const float*)d_in[18];
  const float* m_b_dt = (const float*)d_in[19];
  const float* m_a_log= (const float*)d_in[20];
  const float* m_w_b  = (const float*)d_in[21];
  const float* m_w_c  = (const float*)d_in[22];
  const float* m_d    = (const float*)d_in[23];
  const float* m_w_out= (const float*)d_in[24];
  const float* fn_g   = (const float*)d_in[25];
  const float* fn_b   = (const float*)d_in[26];
  const float* pol_w1 = (const float*)d_in[27];
  const float* pol_b1 = (const float*)d_in[28];
  const float* pol_g  = (const float*)d_in[29];
  const float* pol_bb = (const float*)d_in[30];
  const float* pol_w2 = (const float*)d_in[31];
  const float* pol_b2 = (const float*)d_in[32];
  const int*   pact   = (const int*)d_in[33];

  float* ws  = (float*)d_ws;
  float* X   = ws;                       // NTOK*128
  float* XIN = X   + (size_t)NTOK*128;   // NTOK*128
  float* Z   = XIN + (size_t)NTOK*128;   // NTOK*128
  float* DT  = Z   + (size_t)NTOK*128;   // NTOK*128 (Y aliases this)
  float* BT  = DT  + (size_t)NTOK*128;   // NTOK*8
  float* CT  = BT  + (size_t)NTOK*8;     // NTOK*8
  float* Y   = DT;                       // alias: scan overwrites DT in place
  float* E1  = XIN;                      // alias: NTOK*256 spans XIN+Z, pre-layer only

  const int nblk = NTOK/8;  // 4096

  k_enc1<<<nblk, 256, 0, stream>>>(obs, enc_w1, enc_b1, enc_g1, enc_bb1, E1);
  k_enc2_proj<<<nblk, 128, 0, stream>>>(E1, enc_w2, enc_b2, enc_g2, enc_bb2,
                                        emb, pact, proj_w, proj_b, proj_g, proj_bb, X);
  for (int l = 0; l < NLD; l++){
    k_pre<<<nblk, 256, 0, stream>>>(X,
        m_ln_g + l*128, m_ln_b + l*128,
        m_w_ig + (size_t)l*256*128, m_w_dt + (size_t)l*128*128, m_b_dt + l*128,
        m_w_b + (size_t)l*8*128, m_w_c + (size_t)l*8*128,
        XIN, Z, DT, BT, CT);
    k_scan<<<BB*4, 256, 0, stream>>>(DT, XIN, BT, CT,
        h0 + (size_t)l*BB*DMD*DSD, m_a_log + (size_t)l*DMD*DSD, Y);
    k_post<<<nblk, 128, 0, stream>>>(X, Y, Z, XIN,
        m_d + l*128, m_w_out + (size_t)l*128*128);
  }
  k_head<<<nblk, 128, 0, stream>>>(X, fn_g, fn_b, pol_w1, pol_b1,
                                   pol_g, pol_bb, pol_w2, pol_b2, (float*)d_out);
}

// Round 3
// 969.432 us; speedup vs baseline: 1.5713x; 1.5713x over previous
//
#include <hip/hip_runtime.h>
#include <math.h>

#define BB 64
#define TT 512
#define OBSD 115
#define DMD 128
#define DSD 8
#define NLD 3
#define EMBD 16
#define NAD 19
#define H1D 256
#define NTOK (BB*TT)
#define MT 16   // tokens per GEMM block

__device__ __forceinline__ float wsum(float v){
  #pragma unroll
  for (int o = 1; o < 64; o <<= 1) v += __shfl_xor(v, o, 64);
  return v;
}
__device__ __forceinline__ float silu_f(float x){ return x / (1.f + __expf(-x)); }
__device__ __forceinline__ float softplus_f(float x){
  return fmaxf(x, 0.f) + log1pf(__expf(-fabsf(x)));
}

// ---------------- k_prep: weight transposes into [K4][Npad][4] ----------------
struct PJob { const float* src; float* dst; int N; int K; int Npad; int jofs; };
struct PJobs { PJob j[20]; };

__global__ __launch_bounds__(256) void k_prep(PJobs P){
  const int job = blockIdx.x >> 4;
  const int sub = blockIdx.x & 15;
  PJob pj = P.j[job];
  const int K4 = (pj.K + 3) >> 2;
  const int elems = K4 * pj.N * 4;
  for (int idx = sub*256 + threadIdx.x; idx < elems; idx += 16*256){
    int c = idx & 3;
    int q = idx >> 2;
    int jj = q % pj.N;
    int k4 = q / pj.N;
    int k  = k4*4 + c;
    float v = (k < pj.K) ? pj.src[(size_t)jj*pj.K + k] : 0.f;
    pj.dst[(size_t)k4*pj.Npad*4 + (size_t)(pj.jofs + jj)*4 + c] = v;
  }
}

// ---------------- k_enc1: e1 = silu(LN(obs @ w1.T + b1)) ----------------
__global__ __launch_bounds__(128) void k_enc1(
    const float* __restrict__ obs, const float* __restrict__ w1t,
    const float* __restrict__ b1, const float* __restrict__ g1,
    const float* __restrict__ bb1, float* __restrict__ e1)
{
  __shared__ __align__(16) float s_act[MT][116];
  __shared__ float s_val[MT][257];
  __shared__ float s_mr[MT][2];
  const int tok0 = blockIdx.x * MT;
  const int tid  = threadIdx.x;
  const int wave = tid >> 6, lane = tid & 63;

  for (int idx = tid; idx < MT*OBSD; idx += 128){
    int t = idx / OBSD;
    int k = idx - t*OBSD;
    s_act[t][k] = obs[(size_t)tok0*OBSD + idx];
  }
  if (tid < MT) s_act[tid][115] = 0.f;
  __syncthreads();

  float acc0[MT], acc1[MT];
  #pragma unroll
  for (int t = 0; t < MT; t++){ acc0[t] = 0.f; acc1[t] = 0.f; }

  float4 w0 = *(const float4*)&w1t[(size_t)tid*4];
  float4 w1v = *(const float4*)&w1t[(size_t)(tid+128)*4];
  for (int k4 = 0; k4 < 29; k4++){
    float4 cw0 = w0, cw1 = w1v;
    if (k4 + 1 < 29){
      w0  = *(const float4*)&w1t[(size_t)(k4+1)*1024 + (size_t)tid*4];
      w1v = *(const float4*)&w1t[(size_t)(k4+1)*1024 + (size_t)(tid+128)*4];
    }
    #pragma unroll
    for (int t = 0; t < MT; t++){
      const float4 a = *(const float4*)&s_act[t][k4*4];
      acc0[t] = fmaf(a.x, cw0.x, acc0[t]); acc0[t] = fmaf(a.y, cw0.y, acc0[t]);
      acc0[t] = fmaf(a.z, cw0.z, acc0[t]); acc0[t] = fmaf(a.w, cw0.w, acc0[t]);
      acc1[t] = fmaf(a.x, cw1.x, acc1[t]); acc1[t] = fmaf(a.y, cw1.y, acc1[t]);
      acc1[t] = fmaf(a.z, cw1.z, acc1[t]); acc1[t] = fmaf(a.w, cw1.w, acc1[t]);
    }
  }
  {
    float bias0 = b1[tid], bias1 = b1[tid+128];
    #pragma unroll
    for (int t = 0; t < MT; t++){
      s_val[t][tid]     = acc0[t] + bias0;
      s_val[t][tid+128] = acc1[t] + bias1;
    }
  }
  __syncthreads();

  for (int t = wave*8; t < wave*8 + 8; t++){
    float v0 = s_val[t][lane], v1 = s_val[t][lane+64];
    float v2 = s_val[t][lane+128], v3 = s_val[t][lane+192];
    float m = wsum(v0+v1+v2+v3) * (1.f/256.f);
    float d0=v0-m, d1=v1-m, d2=v2-m, d3=v3-m;
    float var = wsum(d0*d0+d1*d1+d2*d2+d3*d3) * (1.f/256.f);
    if (lane == 0){ s_mr[t][0] = m; s_mr[t][1] = rsqrtf(var + 1e-5f); }
  }
  __syncthreads();
  {
    float ga = g1[tid], gb = g1[tid+128], ca = bb1[tid], cb = bb1[tid+128];
    #pragma unroll
    for (int t = 0; t < MT; t++){
      float m = s_mr[t][0], r = s_mr[t][1];
      e1[(size_t)(tok0+t)*H1D + tid]       = silu_f((s_val[t][tid]     - m)*r*ga + ca);
      e1[(size_t)(tok0+t)*H1D + tid + 128] = silu_f((s_val[t][tid+128] - m)*r*gb + cb);
    }
  }
}

// ------- k_enc2: e2 = LN(e1@w2.T+b2); X = silu(LN([e2,emb[pa]]@pw.T+pb)) -------
__global__ __launch_bounds__(128) void k_enc2(
    const float* __restrict__ e1, const float* __restrict__ w2t,
    const float* __restrict__ b2, const float* __restrict__ g2,
    const float* __restrict__ bb2,
    const float* __restrict__ emb, const int* __restrict__ pact,
    const float* __restrict__ pwt, const float* __restrict__ pb,
    const float* __restrict__ pg, const float* __restrict__ pbb,
    float* __restrict__ X)
{
  __shared__ __align__(16) float s_act[MT][256];
  __shared__ __align__(16) float s_a2[MT][144];
  __shared__ float s_val[MT][129];
  __shared__ float s_mr[MT][2];
  const int tok0 = blockIdx.x * MT;
  const int tid  = threadIdx.x;
  const int wave = tid >> 6, lane = tid & 63;

  for (int idx = tid; idx < MT*256; idx += 128)
    ((float*)s_act)[ (idx>>8)*256 + (idx&255) ] = e1[(size_t)tok0*256 + idx];
  for (int idx = tid; idx < MT*EMBD; idx += 128){
    int t = idx >> 4, k = idx & 15;
    int a = pact[tok0 + t];
    s_a2[t][128 + k] = emb[(size_t)a*EMBD + k];
  }
  __syncthreads();

  float acc[MT];
  #pragma unroll
  for (int t = 0; t < MT; t++) acc[t] = 0.f;
  float4 w = *(const float4*)&w2t[(size_t)tid*4];
  for (int k4 = 0; k4 < 64; k4++){
    float4 cw = w;
    if (k4 + 1 < 64) w = *(const float4*)&w2t[(size_t)(k4+1)*512 + (size_t)tid*4];
    #pragma unroll
    for (int t = 0; t < MT; t++){
      const float4 a = *(const float4*)&s_act[t][k4*4];
      acc[t] = fmaf(a.x, cw.x, acc[t]); acc[t] = fmaf(a.y, cw.y, acc[t]);
      acc[t] = fmaf(a.z, cw.z, acc[t]); acc[t] = fmaf(a.w, cw.w, acc[t]);
    }
  }
  {
    float bias = b2[tid];
    #pragma unroll
    for (int t = 0; t < MT; t++) s_val[t][tid] = acc[t] + bias;
  }
  __syncthreads();

  for (int t = wave*8; t < wave*8 + 8; t++){
    float v0 = s_val[t][lane], v1 = s_val[t][lane+64];
    float m = wsum(v0+v1) * (1.f/128.f);
    float d0=v0-m, d1=v1-m;
    float var = wsum(d0*d0+d1*d1) * (1.f/128.f);
    if (lane == 0){ s_mr[t][0] = m; s_mr[t][1] = rsqrtf(var + 1e-5f); }
  }
  __syncthreads();
  {
    float g = g2[tid], c = bb2[tid];
    #pragma unroll
    for (int t = 0; t < MT; t++)
      s_a2[t][tid] = (s_val[t][tid] - s_mr[t][0]) * s_mr[t][1] * g + c;
  }
  __syncthreads();

  float acc2[MT];
  #pragma unroll
  for (int t = 0; t < MT; t++) acc2[t] = 0.f;
  w = *(const float4*)&pwt[(size_t)tid*4];
  for (int k4 = 0; k4 < 36; k4++){
    float4 cw = w;
    if (k4 + 1 < 36) w = *(const float4*)&pwt[(size_t)(k4+1)*512 + (size_t)tid*4];
    #pragma unroll
    for (int t = 0; t < MT; t++){
      const float4 a = *(const float4*)&s_a2[t][k4*4];
      acc2[t] = fmaf(a.x, cw.x, acc2[t]); acc2[t] = fmaf(a.y, cw.y, acc2[t]);
      acc2[t] = fmaf(a.z, cw.z, acc2[t]); acc2[t] = fmaf(a.w, cw.w, acc2[t]);
    }
  }
  {
    float bias = pb[tid];
    #pragma unroll
    for (int t = 0; t < MT; t++) s_val[t][tid] = acc2[t] + bias;
  }
  __syncthreads();

  for (int t = wave*8; t < wave*8 + 8; t++){
    float v0 = s_val[t][lane], v1 = s_val[t][lane+64];
    float m = wsum(v0+v1) * (1.f/128.f);
    float d0=v0-m, d1=v1-m;
    float var = wsum(d0*d0+d1*d1) * (1.f/128.f);
    if (lane == 0){ s_mr[t][0] = m; s_mr[t][1] = rsqrtf(var + 1e-5f); }
  }
  __syncthreads();
  {
    float g = pg[tid], c = pbb[tid];
    #pragma unroll
    for (int t = 0; t < MT; t++){
      float v = (s_val[t][tid] - s_mr[t][0]) * s_mr[t][1] * g + c;
      X[(size_t)(tok0+t)*DMD + tid] = silu_f(v);
    }
  }
}

// ----- k_pre: xn=LN(x); [x_in,z]=xn@wig.T; dt=softplus(x_in@wdt.T+bdt); bt,ct -----
__global__ __launch_bounds__(128) void k_pre(
    const float* __restrict__ X,
    const float* __restrict__ lng, const float* __restrict__ lnb,
    const float* __restrict__ wigt, const float* __restrict__ wdbct,
    const float* __restrict__ bdt,
    float* __restrict__ XIN, float* __restrict__ Z, float* __restrict__ DT,
    float* __restrict__ BT, float* __restrict__ CT)
{
  __shared__ __align__(16) float s_x[MT][128];
  __shared__ __align__(16) float s_xin[MT][128];
  __shared__ float s_mr[MT][2];
  const int tok0 = blockIdx.x * MT;
  const int tid  = threadIdx.x;
  const int wave = tid >> 6, lane = tid & 63;

  for (int idx = tid; idx < MT*128; idx += 128)
    ((float*)s_x)[idx] = X[(size_t)tok0*128 + idx];
  __syncthreads();

  for (int t = wave*8; t < wave*8 + 8; t++){
    float v0 = s_x[t][lane], v1 = s_x[t][lane+64];
    float m = wsum(v0+v1) * (1.f/128.f);
    float d0=v0-m, d1=v1-m;
    float var = wsum(d0*d0+d1*d1) * (1.f/128.f);
    if (lane == 0){ s_mr[t][0] = m; s_mr[t][1] = rsqrtf(var + 1e-5f); }
  }
  __syncthreads();
  {
    float g = lng[tid], c = lnb[tid];
    #pragma unroll
    for (int t = 0; t < MT; t++)
      s_x[t][tid] = (s_x[t][tid] - s_mr[t][0]) * s_mr[t][1] * g + c;
  }
  __syncthreads();

  // wig: N=256, JW=2 (j=tid -> x_in, j=tid+128 -> z)
  float acc0[MT], acc1[MT];
  #pragma unroll
  for (int t = 0; t < MT; t++){ acc0[t] = 0.f; acc1[t] = 0.f; }
  float4 w0 = *(const float4*)&wigt[(size_t)tid*4];
  float4 w1v = *(const float4*)&wigt[(size_t)(tid+128)*4];
  for (int k4 = 0; k4 < 32; k4++){
    float4 cw0 = w0, cw1 = w1v;
    if (k4 + 1 < 32){
      w0  = *(const float4*)&wigt[(size_t)(k4+1)*1024 + (size_t)tid*4];
      w1v = *(const float4*)&wigt[(size_t)(k4+1)*1024 + (size_t)(tid+128)*4];
    }
    #pragma unroll
    for (int t = 0; t < MT; t++){
      const float4 a = *(const float4*)&s_x[t][k4*4];
      acc0[t] = fmaf(a.x, cw0.x, acc0[t]); acc0[t] = fmaf(a.y, cw0.y, acc0[t]);
      acc0[t] = fmaf(a.z, cw0.z, acc0[t]); acc0[t] = fmaf(a.w, cw0.w, acc0[t]);
      acc1[t] = fmaf(a.x, cw1.x, acc1[t]); acc1[t] = fmaf(a.y, cw1.y, acc1[t]);
      acc1[t] = fmaf(a.z, cw1.z, acc1[t]); acc1[t] = fmaf(a.w, cw1.w, acc1[t]);
    }
  }
  #pragma unroll
  for (int t = 0; t < MT; t++){
    XIN[(size_t)(tok0+t)*128 + tid] = acc0[t];
    s_xin[t][tid] = acc0[t];
    Z[(size_t)(tok0+t)*128 + tid] = acc1[t];
  }
  __syncthreads();

  // wdt over x_in (N=128)
  float acc2[MT];
  #pragma unroll
  for (int t = 0; t < MT; t++) acc2[t] = 0.f;
  float4 w = *(const float4*)&wdbct[(size_t)tid*4];
  for (int k4 = 0; k4 < 32; k4++){
    float4 cw = w;
    if (k4 + 1 < 32) w = *(const float4*)&wdbct[(size_t)(k4+1)*576 + (size_t)tid*4];
    #pragma unroll
    for (int t = 0; t < MT; t++){
      const float4 a = *(const float4*)&s_xin[t][k4*4];
      acc2[t] = fmaf(a.x, cw.x, acc2[t]); acc2[t] = fmaf(a.y, cw.y, acc2[t]);
      acc2[t] = fmaf(a.z, cw.z, acc2[t]); acc2[t] = fmaf(a.w, cw.w, acc2[t]);
    }
  }
  {
    float bd = bdt[tid];
    #pragma unroll
    for (int t = 0; t < MT; t++)
      DT[(size_t)(tok0+t)*128 + tid] = softplus_f(acc2[t] + bd);
  }

  // bt/ct (16 outputs), lanes 0..15 of wave 0
  if (tid < 16){
    float acc3[MT];
    #pragma unroll
    for (int t = 0; t < MT; t++) acc3[t] = 0.f;
    for (int k4 = 0; k4 < 32; k4++){
      const float4 cw = *(const float4*)&wdbct[(size_t)k4*576 + (size_t)(128+tid)*4];
      #pragma unroll
      for (int t = 0; t < MT; t++){
        const float4 a = *(const float4*)&s_xin[t][k4*4];
        acc3[t] = fmaf(a.x, cw.x, acc3[t]); acc3[t] = fmaf(a.y, cw.y, acc3[t]);
        acc3[t] = fmaf(a.z, cw.z, acc3[t]); acc3[t] = fmaf(a.w, cw.w, acc3[t]);
      }
    }
    if (tid < 8){
      #pragma unroll
      for (int t = 0; t < MT; t++) BT[(size_t)(tok0+t)*8 + tid] = acc3[t];
    } else {
      #pragma unroll
      for (int t = 0; t < MT; t++) CT[(size_t)(tok0+t)*8 + (tid-8)] = acc3[t];
    }
  }
}

// ---------------- k_scan: chunked, LDS double-buffered ----------------
__global__ __launch_bounds__(256) void k_scan(
    const float* DT, const float* __restrict__ XIN,
    const float* __restrict__ BT, const float* __restrict__ CT,
    const float* __restrict__ h0, const float* __restrict__ alog,
    float* Y)
{
  __shared__ float s_dxi[2][64][32][2];
  __shared__ float s_bc[2][64][8][2];
  const int blk = blockIdx.x;
  const int b = blk >> 2, dg = blk & 3;
  const int tid = threadIdx.x;
  const int d_sub = tid >> 3, s = tid & 7;
  const int d = dg*32 + d_sub;

  const float A = -__expf(alog[d*DSD + s]);
  float h = h0[b*(DMD*DSD) + d*DSD + s];

  const size_t base  = (size_t)b*TT*128;
  const size_t baseS = (size_t)b*TT*8;

  const int stl = tid >> 5;   // 0..7
  const int sdl = tid & 31;
  const int btl = tid >> 3;   // 0..31
  const int bsl = tid & 7;

  float rdt[8], rxi[8], rbt[2], rct[2];

  auto loadChunk = [&](int c){
    const int t0 = c*64;
    #pragma unroll
    for (int r = 0; r < 8; r++){
      size_t g = base + (size_t)(t0 + stl + r*8)*128 + dg*32 + sdl;
      rdt[r] = DT[g];
      rxi[r] = XIN[g];
    }
    #pragma unroll
    for (int r = 0; r < 2; r++){
      size_t g = baseS + (size_t)(t0 + btl + r*32)*8 + bsl;
      rbt[r] = BT[g];
      rct[r] = CT[g];
    }
  };
  auto writeChunk = [&](int buf){
    #pragma unroll
    for (int r = 0; r < 8; r++){
      s_dxi[buf][stl + r*8][sdl][0] = rdt[r];
      s_dxi[buf][stl + r*8][sdl][1] = rxi[r];
    }
    #pragma unroll
    for (int r = 0; r < 2; r++){
      s_bc[buf][btl + r*32][bsl][0] = rbt[r];
      s_bc[buf][btl + r*32][bsl][1] = rct[r];
    }
  };

  loadChunk(0);
  writeChunk(0);
  __syncthreads();

  for (int c = 0; c < 8; c++){
    const int cur = c & 1;
    if (c < 7) loadChunk(c + 1);
    float* yp = Y + base + (size_t)c*64*128 + d;
    #pragma unroll 4
    for (int t = 0; t < 64; t++){
      float dt = s_dxi[cur][t][d_sub][0];
      float xi = s_dxi[cur][t][d_sub][1];
      float bt = s_bc[cur][t][s][0];
      float ct = s_bc[cur][t][s][1];
      float dA = __expf(dt * A);
      h = fmaf(dA, h, dt*xi*bt);
      float y = h * ct;
      y += __shfl_xor(y, 1, 64);
      y += __shfl_xor(y, 2, 64);
      y += __shfl_xor(y, 4, 64);
      if (s == 0) yp[t*128] = y;
    }
    if (c < 7) writeChunk(cur ^ 1);
    __syncthreads();
  }
}

// ------- k_post: X += (y*silu(z) + x_in*d) @ w_out.T -------
__global__ __launch_bounds__(128) void k_post(
    float* __restrict__ X,
    const float* __restrict__ Y, const float* __restrict__ Z,
    const float* __restrict__ XIN,
    const float* __restrict__ dpar, const float* __restrict__ woutt)
{
  __shared__ __align__(16) float s_ssm[MT][128];
  const int tok0 = blockIdx.x * MT;
  const int tid  = threadIdx.x;

  {
    float dp = dpar[tid];
    #pragma unroll
    for (int t = 0; t < MT; t++){
      size_t g = (size_t)(tok0+t)*128 + tid;
      s_ssm[t][tid] = Y[g]*silu_f(Z[g]) + XIN[g]*dp;
    }
  }
  __syncthreads();

  float acc[MT];
  #pragma unroll
  for (int t = 0; t < MT; t++) acc[t] = 0.f;
  float4 w = *(const float4*)&woutt[(size_t)tid*4];
  for (int k4 = 0; k4 < 32; k4++){
    float4 cw = w;
    if (k4 + 1 < 32) w = *(const float4*)&woutt[(size_t)(k4+1)*512 + (size_t)tid*4];
    #pragma unroll
    for (int t = 0; t < MT; t++){
      const float4 a = *(const float4*)&s_ssm[t][k4*4];
      acc[t] = fmaf(a.x, cw.x, acc[t]); acc[t] = fmaf(a.y, cw.y, acc[t]);
      acc[t] = fmaf(a.z, cw.z, acc[t]); acc[t] = fmaf(a.w, cw.w, acc[t]);
    }
  }
  #pragma unroll
  for (int t = 0; t < MT; t++)
    X[(size_t)(tok0+t)*128 + tid] += acc[t];
}

// ------- k_head: LN(fn); p=silu(LN(x@pw1.T+pb1)); out=p@pw2.T+pb2 -------
__global__ __launch_bounds__(128) void k_head(
    const float* __restrict__ X,
    const float* __restrict__ fng, const float* __restrict__ fnb,
    const float* __restrict__ pw1t, const float* __restrict__ pb1,
    const float* __restrict__ pg, const float* __restrict__ pbb,
    const float* __restrict__ pw2t, const float* __restrict__ pb2,
    float* __restrict__ out)
{
  __shared__ __align__(16) float s_x[MT][128];
  __shared__ float s_val[MT][129];
  __shared__ float s_mr[MT][2];
  const int tok0 = blockIdx.x * MT;
  const int tid  = threadIdx.x;
  const int wave = tid >> 6, lane = tid & 63;

  for (int idx = tid; idx < MT*128; idx += 128)
    ((float*)s_x)[idx] = X[(size_t)tok0*128 + idx];
  __syncthreads();

  for (int t = wave*8; t < wave*8 + 8; t++){
    float v0 = s_x[t][lane], v1 = s_x[t][lane+64];
    float m = wsum(v0+v1) * (1.f/128.f);
    float d0=v0-m, d1=v1-m;
    float var = wsum(d0*d0+d1*d1) * (1.f/128.f);
    if (lane == 0){ s_mr[t][0] = m; s_mr[t][1] = rsqrtf(var + 1e-5f); }
  }
  __syncthreads();
  {
    float g = fng[tid], c = fnb[tid];
    #pragma unroll
    for (int t = 0; t < MT; t++)
      s_x[t][tid] = (s_x[t][tid] - s_mr[t][0]) * s_mr[t][1] * g + c;
  }
  __syncthreads();

  float acc[MT];
  #pragma unroll
  for (int t = 0; t < MT; t++) acc[t] = 0.f;
  float4 w = *(const float4*)&pw1t[(size_t)tid*4];
  for (int k4 = 0; k4 < 32; k4++){
    float4 cw = w;
    if (k4 + 1 < 32) w = *(const float4*)&pw1t[(size_t)(k4+1)*512 + (size_t)tid*4];
    #pragma unroll
    for (int t = 0; t < MT; t++){
      const float4 a = *(const float4*)&s_x[t][k4*4];
      acc[t] = fmaf(a.x, cw.x, acc[t]); acc[t] = fmaf(a.y, cw.y, acc[t]);
      acc[t] = fmaf(a.z, cw.z, acc[t]); acc[t] = fmaf(a.w, cw.w, acc[t]);
    }
  }
  {
    float bias = pb1[tid];
    #pragma unroll
    for (int t = 0; t < MT; t++) s_val[t][tid] = acc[t] + bias;
  }
  __syncthreads();

  for (int t = wave*8; t < wave*8 + 8; t++){
    float v0 = s_val[t][lane], v1 = s_val[t][lane+64];
    float m = wsum(v0+v1) * (1.f/128.f);
    float d0=v0-m, d1=v1-m;
    float var = wsum(d0*d0+d1*d1) * (1.f/128.f);
    if (lane == 0){ s_mr[t][0] = m; s_mr[t][1] = rsqrtf(var + 1e-5f); }
  }
  __syncthreads();
  {
    float g = pg[tid], c = pbb[tid];
    #pragma unroll
    for (int t = 0; t < MT; t++)
      s_x[t][tid] = silu_f((s_val[t][tid] - s_mr[t][0]) * s_mr[t][1] * g + c);
  }
  __syncthreads();

  if (tid < 32){
    float acc2[MT];
    #pragma unroll
    for (int t = 0; t < MT; t++) acc2[t] = 0.f;
    for (int k4 = 0; k4 < 32; k4++){
      const float4 cw = *(const float4*)&pw2t[(size_t)k4*128 + (size_t)tid*4];
      #pragma unroll
      for (int t = 0; t < MT; t++){
        const float4 a = *(const float4*)&s_x[t][k4*4];
        acc2[t] = fmaf(a.x, cw.x, acc2[t]); acc2[t] = fmaf(a.y, cw.y, acc2[t]);
        acc2[t] = fmaf(a.z, cw.z, acc2[t]); acc2[t] = fmaf(a.w, cw.w, acc2[t]);
      }
    }
    if (tid < NAD){
      float pbv = pb2[tid];
      #pragma unroll
      for (int t = 0; t < MT; t++)
        out[(size_t)(tok0+t)*NAD + tid] = acc2[t] + pbv;
    }
  }
}

extern "C" void kernel_launch(void* const* d_in, const int* in_sizes, int n_in,
                              void* d_out, int out_size, void* d_ws, size_t ws_size,
                              hipStream_t stream) {
  const float* obs    = (const float*)d_in[0];
  const float* h0     = (const float*)d_in[1];
  const float* enc_w1 = (const float*)d_in[2];
  const float* enc_b1 = (const float*)d_in[3];
  const float* enc_g1 = (const float*)d_in[4];
  const float* enc_bb1= (const float*)d_in[5];
  const float* enc_w2 = (const float*)d_in[6];
  const float* enc_b2 = (const float*)d_in[7];
  const float* enc_g2 = (const float*)d_in[8];
  const float* enc_bb2= (const float*)d_in[9];
  const float* emb    = (const float*)d_in[10];
  const float* proj_w = (const float*)d_in[11];
  const float* proj_b = (const float*)d_in[12];
  const float* proj_g = (const float*)d_in[13];
  const float* proj_bb= (const float*)d_in[14];
  const float* m_ln_g = (const float*)d_in[15];
  const float* m_ln_b = (const float*)d_in[16];
  const float* m_w_ig = (const float*)d_in[17];
  const float* m_w_dt = (const float*)d_in[18];
  const float* m_b_dt = (const float*)d_in[19];
  const float* m_a_log= (const float*)d_in[20];
  const float* m_w_b  = (const float*)d_in[21];
  const float* m_w_c  = (const float*)d_in[22];
  const float* m_d    = (const float*)d_in[23];
  const float* m_w_out= (const float*)d_in[24];
  const float* fn_g   = (const float*)d_in[25];
  const float* fn_b   = (const float*)d_in[26];
  const float* pol_w1 = (const float*)d_in[27];
  const float* pol_b1 = (const float*)d_in[28];
  const float* pol_g  = (const float*)d_in[29];
  const float* pol_bb = (const float*)d_in[30];
  const float* pol_w2 = (const float*)d_in[31];
  const float* pol_b2 = (const float*)d_in[32];
  const int*   pact   = (const int*)d_in[33];

  float* ws  = (float*)d_ws;
  float* X   = ws;
  float* XIN = X   + (size_t)NTOK*128;
  float* Z   = XIN + (size_t)NTOK*128;
  float* DT  = Z   + (size_t)NTOK*128;
  float* BT  = DT  + (size_t)NTOK*128;
  float* CT  = BT  + (size_t)NTOK*8;
  float* Y   = DT;                       // scan overwrites DT in place
  float* E1  = XIN;                      // spans XIN+Z, pre-layer only

  float* W1T  = CT + (size_t)NTOK*8;
  float* W2T  = W1T  + 29*256*4;
  float* PWT  = W2T  + 64*128*4;
  float* WIGT = PWT  + 36*128*4;
  float* WDBCT= WIGT + 3*32*256*4;
  float* WOUTT= WDBCT+ 3*32*144*4;
  float* PW1T = WOUTT+ 3*32*128*4;
  float* PW2T = PW1T + 32*128*4;

  PJobs P;
  int nj = 0;
  auto add = [&](const float* src, float* dst, int N, int K, int Npad, int jofs){
    P.j[nj].src = src; P.j[nj].dst = dst; P.j[nj].N = N; P.j[nj].K = K;
    P.j[nj].Npad = Npad; P.j[nj].jofs = jofs; nj++;
  };
  add(enc_w1, W1T, 256, 115, 256, 0);
  add(enc_w2, W2T, 128, 256, 128, 0);
  add(proj_w, PWT, 128, 144, 128, 0);
  for (int l = 0; l < NLD; l++)
    add(m_w_ig + (size_t)l*256*128, WIGT + (size_t)l*32*256*4, 256, 128, 256, 0);
  for (int l = 0; l < NLD; l++){
    add(m_w_dt + (size_t)l*128*128, WDBCT + (size_t)l*32*144*4, 128, 128, 144, 0);
    add(m_w_b  + (size_t)l*8*128,   WDBCT + (size_t)l*32*144*4,   8, 128, 144, 128);
    add(m_w_c  + (size_t)l*8*128,   WDBCT + (size_t)l*32*144*4,   8, 128, 144, 136);
  }
  for (int l = 0; l < NLD; l++)
    add(m_w_out + (size_t)l*128*128, WOUTT + (size_t)l*32*128*4, 128, 128, 128, 0);
  add(pol_w1, PW1T, 128, 128, 128, 0);
  add(pol_w2, PW2T,  19, 128,  32, 0);

  const int nblk = NTOK/MT;  // 2048

  k_prep<<<20*16, 256, 0, stream>>>(P);
  k_enc1<<<nblk, 128, 0, stream>>>(obs, W1T, enc_b1, enc_g1, enc_bb1, E1);
  k_enc2<<<nblk, 128, 0, stream>>>(E1, W2T, enc_b2, enc_g2, enc_bb2,
                                   emb, pact, PWT, proj_b, proj_g, proj_bb, X);
  for (int l = 0; l < NLD; l++){
    k_pre<<<nblk, 128, 0, stream>>>(X,
        m_ln_g + l*128, m_ln_b + l*128,
        WIGT + (size_t)l*32*256*4, WDBCT + (size_t)l*32*144*4, m_b_dt + l*128,
        XIN, Z, DT, BT, CT);
    k_scan<<<BB*4, 256, 0, stream>>>(DT, XIN, BT, CT,
        h0 + (size_t)l*BB*DMD*DSD, m_a_log + (size_t)l*DMD*DSD, Y);
    k_post<<<nblk, 128, 0, stream>>>(X, Y, Z, XIN,
        m_d + l*128, WOUTT + (size_t)l*32*128*4);
  }
  k_head<<<nblk, 128, 0, stream>>>(X, fn_g, fn_b, PW1T, pol_b1,
                                   pol_g, pol_bb, PW2T, pol_b2, (float*)d_out);
}

// Round 4
// 657.107 us; speedup vs baseline: 2.3181x; 1.4753x over previous
//
#include <hip/hip_runtime.h>
#include <math.h>

#define BB 64
#define TT 512
#define OBSD 115
#define DMD 128
#define DSD 8
#define NLD 3
#define EMBD 16
#define NAD 19
#define H1D 256
#define NTOK (BB*TT)

typedef unsigned short ushort_t;
typedef __attribute__((ext_vector_type(8))) short short8;
typedef __attribute__((ext_vector_type(4))) float f32x4;

__device__ __forceinline__ float wsum(float v){
  #pragma unroll
  for (int o = 1; o < 64; o <<= 1) v += __shfl_xor(v, o, 64);
  return v;
}
__device__ __forceinline__ float silu_f(float x){ return x / (1.f + __expf(-x)); }
__device__ __forceinline__ float softplus_f(float x){
  return fmaxf(x, 0.f) + log1pf(__expf(-fabsf(x)));
}
__device__ __forceinline__ ushort_t f2bf(float x){
  unsigned u = __float_as_uint(x);
  unsigned r = (u + 0x7fffu + ((u >> 16) & 1u)) >> 16;
  return (ushort_t)r;
}
#define MFMA(a,b,c) __builtin_amdgcn_mfma_f32_16x16x32_bf16((a),(b),(c),0,0,0)

// ---------------- k_prep: fp32 weights -> padded bf16 [Nrow][Kpad] ----------------
struct PJob { const float* src; ushort_t* dst; int N; int K; int Kpad; int rowofs; int Nw; };
struct PJobs { PJob j[20]; };

__global__ __launch_bounds__(256) void k_prep(PJobs P){
  const int job = blockIdx.x >> 2;
  const int sub = blockIdx.x & 3;
  PJob pj = P.j[job];
  const int elems = pj.Nw * pj.Kpad;
  for (int idx = sub*256 + threadIdx.x; idx < elems; idx += 4*256){
    int n = idx / pj.Kpad;
    int k = idx - n*pj.Kpad;
    float v = (n < pj.N && k < pj.K) ? pj.src[(size_t)n*pj.K + k] : 0.f;
    pj.dst[(size_t)(pj.rowofs + n)*pj.Kpad + k] = f2bf(v);
  }
}

// ---------------- k_enc1: e1(bf16) = silu(LN(obs @ w1.T + b1)) ----------------
__global__ __launch_bounds__(256) void k_enc1(
    const float* __restrict__ obs, const ushort_t* __restrict__ w1b,
    const float* __restrict__ b1, const float* __restrict__ g1,
    const float* __restrict__ bb1, ushort_t* __restrict__ e1)
{
  __shared__ ushort_t s_a[32*136];
  __shared__ float s_val[32*257];
  __shared__ float s_mr[32][2];
  const int tok0 = blockIdx.x * 32;
  const int tid = threadIdx.x;
  const int lane = tid & 63, w = tid >> 6;
  const int q = lane >> 4, cn = lane & 15;
  const int m0 = (w & 1) * 16, nh = w >> 1;

  // stage obs -> bf16 LDS [32][128], zero-pad k>=115
  for (int e = tid; e < 32*16; e += 256){
    int t = e >> 4, kc = e & 15;
    const float* op = obs + (size_t)(tok0 + t)*OBSD;
    short8 v;
    #pragma unroll
    for (int j = 0; j < 8; j++){
      int k = kc*8 + j;
      v[j] = (short)f2bf(k < OBSD ? op[k] : 0.f);
    }
    *(short8*)&s_a[t*136 + kc*8] = v;
  }
  __syncthreads();

  short8 af[4];
  #pragma unroll
  for (int ks = 0; ks < 4; ks++)
    af[ks] = *(const short8*)&s_a[(m0 + cn)*136 + ks*32 + q*8];

  #pragma unroll
  for (int nt = 0; nt < 8; nt++){
    const int n0 = (nh*8 + nt) * 16;
    f32x4 acc = {0.f,0.f,0.f,0.f};
    #pragma unroll
    for (int ks = 0; ks < 4; ks++){
      short8 bf = *(const short8*)&w1b[(size_t)(n0 + cn)*128 + ks*32 + q*8];
      acc = MFMA(af[ks], bf, acc);
    }
    float bias = b1[n0 + cn];
    #pragma unroll
    for (int r = 0; r < 4; r++)
      s_val[(m0 + q*4 + r)*257 + n0 + cn] = acc[r] + bias;
  }
  __syncthreads();

  for (int t = w*8; t < w*8 + 8; t++){
    float v0 = s_val[t*257 + lane],     v1 = s_val[t*257 + lane + 64];
    float v2 = s_val[t*257 + lane+128], v3 = s_val[t*257 + lane + 192];
    float m = wsum(v0+v1+v2+v3) * (1.f/256.f);
    float d0=v0-m, d1=v1-m, d2=v2-m, d3=v3-m;
    float var = wsum(d0*d0+d1*d1+d2*d2+d3*d3) * (1.f/256.f);
    if (lane == 0){ s_mr[t][0] = m; s_mr[t][1] = rsqrtf(var + 1e-5f); }
  }
  __syncthreads();
  for (int e = tid; e < 32*256; e += 256){
    int t = e >> 8, c = e & 255;
    float v = (s_val[t*257 + c] - s_mr[t][0]) * s_mr[t][1] * g1[c] + bb1[c];
    e1[(size_t)(tok0 + t)*256 + c] = f2bf(silu_f(v));
  }
}

// ------- k_enc2: e2=LN(e1@w2.T+b2); X=silu(LN([e2,emb[pa]]@pw.T+pb)) -------
__global__ __launch_bounds__(256) void k_enc2(
    const ushort_t* __restrict__ e1, const ushort_t* __restrict__ w2b,
    const float* __restrict__ b2, const float* __restrict__ g2,
    const float* __restrict__ bb2,
    const float* __restrict__ emb, const int* __restrict__ pact,
    const ushort_t* __restrict__ pwb, const float* __restrict__ pb,
    const float* __restrict__ pg, const float* __restrict__ pbb,
    float* __restrict__ X)
{
  __shared__ float s_val[32*129];
  __shared__ ushort_t s_a[32*168];
  __shared__ float s_mr[32][2];
  const int tok0 = blockIdx.x * 32;
  const int tid = threadIdx.x;
  const int lane = tid & 63, w = tid >> 6;
  const int q = lane >> 4, cn = lane & 15;
  const int m0 = (w & 1) * 16, nh = w >> 1;

  // GEMM1: A directly from global e1 (bf16 [tok][256]); K=256 -> 8 steps
  short8 af[8];
  #pragma unroll
  for (int ks = 0; ks < 8; ks++)
    af[ks] = *(const short8*)&e1[(size_t)(tok0 + m0 + cn)*256 + ks*32 + q*8];

  #pragma unroll
  for (int nt = 0; nt < 4; nt++){
    const int n0 = (nh*4 + nt) * 16;
    f32x4 acc = {0.f,0.f,0.f,0.f};
    #pragma unroll
    for (int ks = 0; ks < 8; ks++){
      short8 bf = *(const short8*)&w2b[(size_t)(n0 + cn)*256 + ks*32 + q*8];
      acc = MFMA(af[ks], bf, acc);
    }
    float bias = b2[n0 + cn];
    #pragma unroll
    for (int r = 0; r < 4; r++)
      s_val[(m0 + q*4 + r)*129 + n0 + cn] = acc[r] + bias;
  }
  // emb -> s_a cols 128..159 (144..159 zero-pad)
  for (int e = tid; e < 32*32; e += 256){
    int t = e >> 5, k = e & 31;
    float v = 0.f;
    if (k < EMBD){ int a = pact[tok0 + t]; v = emb[(size_t)a*EMBD + k]; }
    s_a[t*168 + 128 + k] = f2bf(v);
  }
  __syncthreads();

  for (int t = w*8; t < w*8 + 8; t++){
    float v0 = s_val[t*129 + lane], v1 = s_val[t*129 + lane + 64];
    float m = wsum(v0+v1) * (1.f/128.f);
    float d0=v0-m, d1=v1-m;
    float var = wsum(d0*d0+d1*d1) * (1.f/128.f);
    if (lane == 0){ s_mr[t][0] = m; s_mr[t][1] = rsqrtf(var + 1e-5f); }
  }
  __syncthreads();
  for (int e = tid; e < 32*128; e += 256){
    int t = e >> 7, c = e & 127;
    float v = (s_val[t*129 + c] - s_mr[t][0]) * s_mr[t][1] * g2[c] + bb2[c];
    s_a[t*168 + c] = f2bf(v);
  }
  __syncthreads();

  // GEMM2: proj, Kpad=160 -> 5 steps, N=128
  short8 af2[5];
  #pragma unroll
  for (int ks = 0; ks < 5; ks++)
    af2[ks] = *(const short8*)&s_a[(m0 + cn)*168 + ks*32 + q*8];

  #pragma unroll
  for (int nt = 0; nt < 4; nt++){
    const int n0 = (nh*4 + nt) * 16;
    f32x4 acc = {0.f,0.f,0.f,0.f};
    #pragma unroll
    for (int ks = 0; ks < 5; ks++){
      short8 bf = *(const short8*)&pwb[(size_t)(n0 + cn)*160 + ks*32 + q*8];
      acc = MFMA(af2[ks], bf, acc);
    }
    float bias = pb[n0 + cn];
    #pragma unroll
    for (int r = 0; r < 4; r++)
      s_val[(m0 + q*4 + r)*129 + n0 + cn] = acc[r] + bias;
  }
  __syncthreads();

  for (int t = w*8; t < w*8 + 8; t++){
    float v0 = s_val[t*129 + lane], v1 = s_val[t*129 + lane + 64];
    float m = wsum(v0+v1) * (1.f/128.f);
    float d0=v0-m, d1=v1-m;
    float var = wsum(d0*d0+d1*d1) * (1.f/128.f);
    if (lane == 0){ s_mr[t][0] = m; s_mr[t][1] = rsqrtf(var + 1e-5f); }
  }
  __syncthreads();
  for (int e = tid; e < 32*128; e += 256){
    int t = e >> 7, c = e & 127;
    float v = (s_val[t*129 + c] - s_mr[t][0]) * s_mr[t][1] * pg[c] + pbb[c];
    X[(size_t)tok0*128 + e] = silu_f(v);
  }
}

// ----- k_pre: xn=LN(x); [x_in,z]=xn@wig.T; dt=softplus(x_in@wdt.T+bdt); bt,ct -----
__global__ __launch_bounds__(256) void k_pre(
    const float* __restrict__ X,
    const float* __restrict__ lng, const float* __restrict__ lnb,
    const ushort_t* __restrict__ wigb, const ushort_t* __restrict__ wdbcb,
    const float* __restrict__ bdt,
    float* __restrict__ XIN, float* __restrict__ Z, float* __restrict__ DT,
    float* __restrict__ BT, float* __restrict__ CT)
{
  __shared__ float s_val[32*129];
  __shared__ ushort_t s_a[32*136];
  __shared__ ushort_t s_xin[32*136];
  __shared__ float s_mr[32][2];
  const int tok0 = blockIdx.x * 32;
  const int tid = threadIdx.x;
  const int lane = tid & 63, w = tid >> 6;
  const int q = lane >> 4, cn = lane & 15;
  const int m0 = (w & 1) * 16, nh = w >> 1;

  for (int e = tid; e < 32*128; e += 256){
    int t = e >> 7, c = e & 127;
    s_val[t*129 + c] = X[(size_t)tok0*128 + e];
  }
  __syncthreads();

  for (int t = w*8; t < w*8 + 8; t++){
    float v0 = s_val[t*129 + lane], v1 = s_val[t*129 + lane + 64];
    float m = wsum(v0+v1) * (1.f/128.f);
    float d0=v0-m, d1=v1-m;
    float var = wsum(d0*d0+d1*d1) * (1.f/128.f);
    if (lane == 0){ s_mr[t][0] = m; s_mr[t][1] = rsqrtf(var + 1e-5f); }
  }
  __syncthreads();
  for (int e = tid; e < 32*128; e += 256){
    int t = e >> 7, c = e & 127;
    float v = (s_val[t*129 + c] - s_mr[t][0]) * s_mr[t][1] * lng[c] + lnb[c];
    s_a[t*136 + c] = f2bf(v);
  }
  __syncthreads();

  // GEMM1: wig, N=256, K=128; waves nh=0 -> cols 0..127 (x_in), nh=1 -> z
  short8 af[4];
  #pragma unroll
  for (int ks = 0; ks < 4; ks++)
    af[ks] = *(const short8*)&s_a[(m0 + cn)*136 + ks*32 + q*8];

  #pragma unroll
  for (int nt = 0; nt < 8; nt++){
    const int n0 = (nh*8 + nt) * 16;
    f32x4 acc = {0.f,0.f,0.f,0.f};
    #pragma unroll
    for (int ks = 0; ks < 4; ks++){
      short8 bf = *(const short8*)&wigb[(size_t)(n0 + cn)*128 + ks*32 + q*8];
      acc = MFMA(af[ks], bf, acc);
    }
    if (n0 < 128){
      #pragma unroll
      for (int r = 0; r < 4; r++){
        int tr = m0 + q*4 + r;
        XIN[(size_t)(tok0 + tr)*128 + n0 + cn] = acc[r];
        s_xin[tr*136 + n0 + cn] = f2bf(acc[r]);
      }
    } else {
      #pragma unroll
      for (int r = 0; r < 4; r++){
        int tr = m0 + q*4 + r;
        Z[(size_t)(tok0 + tr)*128 + (n0 - 128) + cn] = acc[r];
      }
    }
  }
  __syncthreads();

  // GEMM2: [wdt;wb;wc] 144 rows, K=128 -> 9 n-tiles
  short8 af2[4];
  #pragma unroll
  for (int ks = 0; ks < 4; ks++)
    af2[ks] = *(const short8*)&s_xin[(m0 + cn)*136 + ks*32 + q*8];

  for (int nt = nh; nt < 9; nt += 2){
    const int n0 = nt * 16;
    f32x4 acc = {0.f,0.f,0.f,0.f};
    #pragma unroll
    for (int ks = 0; ks < 4; ks++){
      short8 bf = *(const short8*)&wdbcb[(size_t)(n0 + cn)*128 + ks*32 + q*8];
      acc = MFMA(af2[ks], bf, acc);
    }
    const int col = n0 + cn;
    if (col < 128){
      float bd = bdt[col];
      #pragma unroll
      for (int r = 0; r < 4; r++)
        DT[(size_t)(tok0 + m0 + q*4 + r)*128 + col] = softplus_f(acc[r] + bd);
    } else if (col < 136){
      #pragma unroll
      for (int r = 0; r < 4; r++)
        BT[(size_t)(tok0 + m0 + q*4 + r)*8 + (col - 128)] = acc[r];
    } else {
      #pragma unroll
      for (int r = 0; r < 4; r++)
        CT[(size_t)(tok0 + m0 + q*4 + r)*8 + (col - 136)] = acc[r];
    }
  }
}

// ---------------- k_scan: chunked, LDS double-buffered (unchanged) ----------------
__global__ __launch_bounds__(256) void k_scan(
    const float* DT, const float* __restrict__ XIN,
    const float* __restrict__ BT, const float* __restrict__ CT,
    const float* __restrict__ h0, const float* __restrict__ alog,
    float* Y)
{
  __shared__ float s_dxi[2][64][32][2];
  __shared__ float s_bc[2][64][8][2];
  const int blk = blockIdx.x;
  const int b = blk >> 2, dg = blk & 3;
  const int tid = threadIdx.x;
  const int d_sub = tid >> 3, s = tid & 7;
  const int d = dg*32 + d_sub;

  const float A = -__expf(alog[d*DSD + s]);
  float h = h0[b*(DMD*DSD) + d*DSD + s];

  const size_t base  = (size_t)b*TT*128;
  const size_t baseS = (size_t)b*TT*8;

  const int stl = tid >> 5;
  const int sdl = tid & 31;
  const int btl = tid >> 3;
  const int bsl = tid & 7;

  float rdt[8], rxi[8], rbt[2], rct[2];

  auto loadChunk = [&](int c){
    const int t0 = c*64;
    #pragma unroll
    for (int r = 0; r < 8; r++){
      size_t g = base + (size_t)(t0 + stl + r*8)*128 + dg*32 + sdl;
      rdt[r] = DT[g];
      rxi[r] = XIN[g];
    }
    #pragma unroll
    for (int r = 0; r < 2; r++){
      size_t g = baseS + (size_t)(t0 + btl + r*32)*8 + bsl;
      rbt[r] = BT[g];
      rct[r] = CT[g];
    }
  };
  auto writeChunk = [&](int buf){
    #pragma unroll
    for (int r = 0; r < 8; r++){
      s_dxi[buf][stl + r*8][sdl][0] = rdt[r];
      s_dxi[buf][stl + r*8][sdl][1] = rxi[r];
    }
    #pragma unroll
    for (int r = 0; r < 2; r++){
      s_bc[buf][btl + r*32][bsl][0] = rbt[r];
      s_bc[buf][btl + r*32][bsl][1] = rct[r];
    }
  };

  loadChunk(0);
  writeChunk(0);
  __syncthreads();

  for (int c = 0; c < 8; c++){
    const int cur = c & 1;
    if (c < 7) loadChunk(c + 1);
    float* yp = Y + base + (size_t)c*64*128 + d;
    #pragma unroll 4
    for (int t = 0; t < 64; t++){
      float dt = s_dxi[cur][t][d_sub][0];
      float xi = s_dxi[cur][t][d_sub][1];
      float bt = s_bc[cur][t][s][0];
      float ct = s_bc[cur][t][s][1];
      float dA = __expf(dt * A);
      h = fmaf(dA, h, dt*xi*bt);
      float y = h * ct;
      y += __shfl_xor(y, 1, 64);
      y += __shfl_xor(y, 2, 64);
      y += __shfl_xor(y, 4, 64);
      if (s == 0) yp[t*128] = y;
    }
    if (c < 7) writeChunk(cur ^ 1);
    __syncthreads();
  }
}

// ------- k_post: X += (y*silu(z) + x_in*d) @ w_out.T -------
__global__ __launch_bounds__(256) void k_post(
    float* __restrict__ X,
    const float* __restrict__ Y, const float* __restrict__ Z,
    const float* __restrict__ XIN,
    const float* __restrict__ dpar, const ushort_t* __restrict__ woutb)
{
  __shared__ ushort_t s_a[32*136];
  const int tok0 = blockIdx.x * 32;
  const int tid = threadIdx.x;
  const int lane = tid & 63, w = tid >> 6;
  const int q = lane >> 4, cn = lane & 15;
  const int m0 = (w & 1) * 16, nh = w >> 1;

  for (int e = tid; e < 32*128; e += 256){
    int t = e >> 7, c = e & 127;
    size_t g = (size_t)tok0*128 + e;
    float ssm = Y[g]*silu_f(Z[g]) + XIN[g]*dpar[c];
    s_a[t*136 + c] = f2bf(ssm);
  }
  __syncthreads();

  short8 af[4];
  #pragma unroll
  for (int ks = 0; ks < 4; ks++)
    af[ks] = *(const short8*)&s_a[(m0 + cn)*136 + ks*32 + q*8];

  #pragma unroll
  for (int nt = 0; nt < 4; nt++){
    const int n0 = (nh*4 + nt) * 16;
    f32x4 acc = {0.f,0.f,0.f,0.f};
    #pragma unroll
    for (int ks = 0; ks < 4; ks++){
      short8 bf = *(const short8*)&woutb[(size_t)(n0 + cn)*128 + ks*32 + q*8];
      acc = MFMA(af[ks], bf, acc);
    }
    #pragma unroll
    for (int r = 0; r < 4; r++){
      size_t g = (size_t)(tok0 + m0 + q*4 + r)*128 + n0 + cn;
      X[g] += acc[r];
    }
  }
}

// ------- k_head: LN(fn); p=silu(LN(x@pw1.T+pb1)); out=p@pw2.T+pb2 -------
__global__ __launch_bounds__(256) void k_head(
    const float* __restrict__ X,
    const float* __restrict__ fng, const float* __restrict__ fnb,
    const ushort_t* __restrict__ pw1b, const float* __restrict__ pb1,
    const float* __restrict__ pg, const float* __restrict__ pbb,
    const ushort_t* __restrict__ pw2b, const float* __restrict__ pb2,
    float* __restrict__ out)
{
  __shared__ float s_val[32*129];
  __shared__ ushort_t s_a[32*136];
  __shared__ float s_mr[32][2];
  const int tok0 = blockIdx.x * 32;
  const int tid = threadIdx.x;
  const int lane = tid & 63, w = tid >> 6;
  const int q = lane >> 4, cn = lane & 15;
  const int m0 = (w & 1) * 16, nh = w >> 1;

  for (int e = tid; e < 32*128; e += 256){
    int t = e >> 7, c = e & 127;
    s_val[t*129 + c] = X[(size_t)tok0*128 + e];
  }
  __syncthreads();

  for (int t = w*8; t < w*8 + 8; t++){
    float v0 = s_val[t*129 + lane], v1 = s_val[t*129 + lane + 64];
    float m = wsum(v0+v1) * (1.f/128.f);
    float d0=v0-m, d1=v1-m;
    float var = wsum(d0*d0+d1*d1) * (1.f/128.f);
    if (lane == 0){ s_mr[t][0] = m; s_mr[t][1] = rsqrtf(var + 1e-5f); }
  }
  __syncthreads();
  for (int e = tid; e < 32*128; e += 256){
    int t = e >> 7, c = e & 127;
    float v = (s_val[t*129 + c] - s_mr[t][0]) * s_mr[t][1] * fng[c] + fnb[c];
    s_a[t*136 + c] = f2bf(v);
  }
  __syncthreads();

  short8 af[4];
  #pragma unroll
  for (int ks = 0; ks < 4; ks++)
    af[ks] = *(const short8*)&s_a[(m0 + cn)*136 + ks*32 + q*8];

  #pragma unroll
  for (int nt = 0; nt < 4; nt++){
    const int n0 = (nh*4 + nt) * 16;
    f32x4 acc = {0.f,0.f,0.f,0.f};
    #pragma unroll
    for (int ks = 0; ks < 4; ks++){
      short8 bf = *(const short8*)&pw1b[(size_t)(n0 + cn)*128 + ks*32 + q*8];
      acc = MFMA(af[ks], bf, acc);
    }
    float bias = pb1[n0 + cn];
    #pragma unroll
    for (int r = 0; r < 4; r++)
      s_val[(m0 + q*4 + r)*129 + n0 + cn] = acc[r] + bias;
  }
  __syncthreads();

  for (int t = w*8; t < w*8 + 8; t++){
    float v0 = s_val[t*129 + lane], v1 = s_val[t*129 + lane + 64];
    float m = wsum(v0+v1) * (1.f/128.f);
    float d0=v0-m, d1=v1-m;
    float var = wsum(d0*d0+d1*d1) * (1.f/128.f);
    if (lane == 0){ s_mr[t][0] = m; s_mr[t][1] = rsqrtf(var + 1e-5f); }
  }
  __syncthreads();
  for (int e = tid; e < 32*128; e += 256){
    int t = e >> 7, c = e & 127;
    float v = (s_val[t*129 + c] - s_mr[t][0]) * s_mr[t][1] * pg[c] + pbb[c];
    s_a[t*136 + c] = f2bf(silu_f(v));
  }
  __syncthreads();

  // GEMM2: pol_w2 padded to [32][128]; wave nh handles n-tile nh
  short8 af2[4];
  #pragma unroll
  for (int ks = 0; ks < 4; ks++)
    af2[ks] = *(const short8*)&s_a[(m0 + cn)*136 + ks*32 + q*8];

  {
    const int n0 = nh * 16;
    f32x4 acc = {0.f,0.f,0.f,0.f};
    #pragma unroll
    for (int ks = 0; ks < 4; ks++){
      short8 bf = *(const short8*)&pw2b[(size_t)(n0 + cn)*128 + ks*32 + q*8];
      acc = MFMA(af2[ks], bf, acc);
    }
    const int col = n0 + cn;
    if (col < NAD){
      float bias = pb2[col];
      #pragma unroll
      for (int r = 0; r < 4; r++)
        out[(size_t)(tok0 + m0 + q*4 + r)*NAD + col] = acc[r] + bias;
    }
  }
}

extern "C" void kernel_launch(void* const* d_in, const int* in_sizes, int n_in,
                              void* d_out, int out_size, void* d_ws, size_t ws_size,
                              hipStream_t stream) {
  const float* obs    = (const float*)d_in[0];
  const float* h0     = (const float*)d_in[1];
  const float* enc_w1 = (const float*)d_in[2];
  const float* enc_b1 = (const float*)d_in[3];
  const float* enc_g1 = (const float*)d_in[4];
  const float* enc_bb1= (const float*)d_in[5];
  const float* enc_w2 = (const float*)d_in[6];
  const float* enc_b2 = (const float*)d_in[7];
  const float* enc_g2 = (const float*)d_in[8];
  const float* enc_bb2= (const float*)d_in[9];
  const float* emb    = (const float*)d_in[10];
  const float* proj_w = (const float*)d_in[11];
  const float* proj_b = (const float*)d_in[12];
  const float* proj_g = (const float*)d_in[13];
  const float* proj_bb= (const float*)d_in[14];
  const float* m_ln_g = (const float*)d_in[15];
  const float* m_ln_b = (const float*)d_in[16];
  const float* m_w_ig = (const float*)d_in[17];
  const float* m_w_dt = (const float*)d_in[18];
  const float* m_b_dt = (const float*)d_in[19];
  const float* m_a_log= (const float*)d_in[20];
  const float* m_w_b  = (const float*)d_in[21];
  const float* m_w_c  = (const float*)d_in[22];
  const float* m_d    = (const float*)d_in[23];
  const float* m_w_out= (const float*)d_in[24];
  const float* fn_g   = (const float*)d_in[25];
  const float* fn_b   = (const float*)d_in[26];
  const float* pol_w1 = (const float*)d_in[27];
  const float* pol_b1 = (const float*)d_in[28];
  const float* pol_g  = (const float*)d_in[29];
  const float* pol_bb = (const float*)d_in[30];
  const float* pol_w2 = (const float*)d_in[31];
  const float* pol_b2 = (const float*)d_in[32];
  const int*   pact   = (const int*)d_in[33];

  float* ws  = (float*)d_ws;
  float* X   = ws;
  float* XIN = X   + (size_t)NTOK*128;
  float* Z   = XIN + (size_t)NTOK*128;
  float* DT  = Z   + (size_t)NTOK*128;
  float* BT  = DT  + (size_t)NTOK*128;
  float* CT  = BT  + (size_t)NTOK*8;
  float* Y   = DT;                          // scan overwrites DT in place
  ushort_t* E1 = (ushort_t*)XIN;            // bf16 [NTOK][256] == NTOK*128 floats

  ushort_t* W1B   = (ushort_t*)(CT + (size_t)NTOK*8);
  ushort_t* W2B   = W1B   + 256*128;
  ushort_t* PWB   = W2B   + 128*256;
  ushort_t* WIGB  = PWB   + 128*160;
  ushort_t* WDBCB = WIGB  + 3*256*128;
  ushort_t* WOUTB = WDBCB + 3*144*128;
  ushort_t* PW1B  = WOUTB + 3*128*128;
  ushort_t* PW2B  = PW1B  + 128*128;

  PJobs P;
  int nj = 0;
  auto add = [&](const float* src, ushort_t* dst, int N, int K, int Kpad, int rowofs, int Nw){
    P.j[nj].src = src; P.j[nj].dst = dst; P.j[nj].N = N; P.j[nj].K = K;
    P.j[nj].Kpad = Kpad; P.j[nj].rowofs = rowofs; P.j[nj].Nw = Nw; nj++;
  };
  add(enc_w1, W1B, 256, 115, 128, 0, 256);
  add(enc_w2, W2B, 128, 256, 256, 0, 128);
  add(proj_w, PWB, 128, 144, 160, 0, 128);
  for (int l = 0; l < NLD; l++)
    add(m_w_ig + (size_t)l*256*128, WIGB + (size_t)l*256*128, 256, 128, 128, 0, 256);
  for (int l = 0; l < NLD; l++){
    add(m_w_dt + (size_t)l*128*128, WDBCB + (size_t)l*144*128, 128, 128, 128, 0,   128);
    add(m_w_b  + (size_t)l*8*128,   WDBCB + (size_t)l*144*128,   8, 128, 128, 128,   8);
    add(m_w_c  + (size_t)l*8*128,   WDBCB + (size_t)l*144*128,   8, 128, 128, 136,   8);
  }
  for (int l = 0; l < NLD; l++)
    add(m_w_out + (size_t)l*128*128, WOUTB + (size_t)l*128*128, 128, 128, 128, 0, 128);
  add(pol_w1, PW1B, 128, 128, 128, 0, 128);
  add(pol_w2, PW2B,  19, 128, 128, 0,  32);

  const int nblk = NTOK/32;  // 1024

  k_prep<<<20*4, 256, 0, stream>>>(P);
  k_enc1<<<nblk, 256, 0, stream>>>(obs, W1B, enc_b1, enc_g1, enc_bb1, E1);
  k_enc2<<<nblk, 256, 0, stream>>>(E1, W2B, enc_b2, enc_g2, enc_bb2,
                                   emb, pact, PWB, proj_b, proj_g, proj_bb, X);
  for (int l = 0; l < NLD; l++){
    k_pre<<<nblk, 256, 0, stream>>>(X,
        m_ln_g + l*128, m_ln_b + l*128,
        WIGB + (size_t)l*256*128, WDBCB + (size_t)l*144*128, m_b_dt + l*128,
        XIN, Z, DT, BT, CT);
    k_scan<<<BB*4, 256, 0, stream>>>(DT, XIN, BT, CT,
        h0 + (size_t)l*BB*DMD*DSD, m_a_log + (size_t)l*DMD*DSD, Y);
    k_post<<<nblk, 256, 0, stream>>>(X, Y, Z, XIN,
        m_d + l*128, WOUTB + (size_t)l*128*128);
  }
  k_head<<<nblk, 256, 0, stream>>>(X, fn_g, fn_b, PW1B, pol_b1,
                                   pol_g, pol_bb, PW2B, pol_b2, (float*)d_out);
}

// Round 5
// 548.943 us; speedup vs baseline: 2.7749x; 1.1970x over previous
//
#include <hip/hip_runtime.h>
#include <math.h>

#define BB 64
#define TT 512
#define OBSD 115
#define DMD 128
#define DSD 8
#define NLD 3
#define EMBD 16
#define NAD 19
#define H1D 256
#define NTOK (BB*TT)
#define SSEG 8
#define TSEG (TT/SSEG)   // 64

typedef unsigned short ushort_t;
typedef __attribute__((ext_vector_type(8))) short short8;
typedef __attribute__((ext_vector_type(4))) float f32x4;

__device__ __forceinline__ float wsum(float v){
  #pragma unroll
  for (int o = 1; o < 64; o <<= 1) v += __shfl_xor(v, o, 64);
  return v;
}
__device__ __forceinline__ float silu_f(float x){ return x / (1.f + __expf(-x)); }
__device__ __forceinline__ float softplus_f(float x){
  return fmaxf(x, 0.f) + log1pf(__expf(-fabsf(x)));
}
__device__ __forceinline__ ushort_t f2bf(float x){
  unsigned u = __float_as_uint(x);
  unsigned r = (u + 0x7fffu + ((u >> 16) & 1u)) >> 16;
  return (ushort_t)r;
}
#define MFMA(a,b,c) __builtin_amdgcn_mfma_f32_16x16x32_bf16((a),(b),(c),0,0,0)

// ---------------- k_prep: fp32 weights -> padded bf16 [Nrow][Kpad] ----------------
struct PJob { const float* src; ushort_t* dst; int N; int K; int Kpad; int rowofs; int Nw; };
struct PJobs { PJob j[20]; };

__global__ __launch_bounds__(256) void k_prep(PJobs P){
  const int job = blockIdx.x >> 2;
  const int sub = blockIdx.x & 3;
  PJob pj = P.j[job];
  const int elems = pj.Nw * pj.Kpad;
  for (int idx = sub*256 + threadIdx.x; idx < elems; idx += 4*256){
    int n = idx / pj.Kpad;
    int k = idx - n*pj.Kpad;
    float v = (n < pj.N && k < pj.K) ? pj.src[(size_t)n*pj.K + k] : 0.f;
    pj.dst[(size_t)(pj.rowofs + n)*pj.Kpad + k] = f2bf(v);
  }
}

// ---------------- k_enc1: e1(bf16) = silu(LN(obs @ w1.T + b1)) ----------------
__global__ __launch_bounds__(256) void k_enc1(
    const float* __restrict__ obs, const ushort_t* __restrict__ w1b,
    const float* __restrict__ b1, const float* __restrict__ g1,
    const float* __restrict__ bb1, ushort_t* __restrict__ e1)
{
  __shared__ ushort_t s_a[32*136];
  __shared__ float s_val[32*257];
  __shared__ float s_mr[32][2];
  const int tok0 = blockIdx.x * 32;
  const int tid = threadIdx.x;
  const int lane = tid & 63, w = tid >> 6;
  const int q = lane >> 4, cn = lane & 15;
  const int m0 = (w & 1) * 16, nh = w >> 1;

  for (int e = tid; e < 32*16; e += 256){
    int t = e >> 4, kc = e & 15;
    const float* op = obs + (size_t)(tok0 + t)*OBSD;
    short8 v;
    #pragma unroll
    for (int j = 0; j < 8; j++){
      int k = kc*8 + j;
      v[j] = (short)f2bf(k < OBSD ? op[k] : 0.f);
    }
    *(short8*)&s_a[t*136 + kc*8] = v;
  }
  __syncthreads();

  short8 af[4];
  #pragma unroll
  for (int ks = 0; ks < 4; ks++)
    af[ks] = *(const short8*)&s_a[(m0 + cn)*136 + ks*32 + q*8];

  #pragma unroll
  for (int nt = 0; nt < 8; nt++){
    const int n0 = (nh*8 + nt) * 16;
    f32x4 acc = {0.f,0.f,0.f,0.f};
    #pragma unroll
    for (int ks = 0; ks < 4; ks++){
      short8 bf = *(const short8*)&w1b[(size_t)(n0 + cn)*128 + ks*32 + q*8];
      acc = MFMA(af[ks], bf, acc);
    }
    float bias = b1[n0 + cn];
    #pragma unroll
    for (int r = 0; r < 4; r++)
      s_val[(m0 + q*4 + r)*257 + n0 + cn] = acc[r] + bias;
  }
  __syncthreads();

  for (int t = w*8; t < w*8 + 8; t++){
    float v0 = s_val[t*257 + lane],     v1 = s_val[t*257 + lane + 64];
    float v2 = s_val[t*257 + lane+128], v3 = s_val[t*257 + lane + 192];
    float m = wsum(v0+v1+v2+v3) * (1.f/256.f);
    float d0=v0-m, d1=v1-m, d2=v2-m, d3=v3-m;
    float var = wsum(d0*d0+d1*d1+d2*d2+d3*d3) * (1.f/256.f);
    if (lane == 0){ s_mr[t][0] = m; s_mr[t][1] = rsqrtf(var + 1e-5f); }
  }
  __syncthreads();
  for (int e = tid; e < 32*256; e += 256){
    int t = e >> 8, c = e & 255;
    float v = (s_val[t*257 + c] - s_mr[t][0]) * s_mr[t][1] * g1[c] + bb1[c];
    e1[(size_t)(tok0 + t)*256 + c] = f2bf(silu_f(v));
  }
}

// ------- k_enc2: e2=LN(e1@w2.T+b2); X=silu(LN([e2,emb[pa]]@pw.T+pb)) -------
__global__ __launch_bounds__(256) void k_enc2(
    const ushort_t* __restrict__ e1, const ushort_t* __restrict__ w2b,
    const float* __restrict__ b2, const float* __restrict__ g2,
    const float* __restrict__ bb2,
    const float* __restrict__ emb, const int* __restrict__ pact,
    const ushort_t* __restrict__ pwb, const float* __restrict__ pb,
    const float* __restrict__ pg, const float* __restrict__ pbb,
    float* __restrict__ X)
{
  __shared__ float s_val[32*129];
  __shared__ ushort_t s_a[32*168];
  __shared__ float s_mr[32][2];
  const int tok0 = blockIdx.x * 32;
  const int tid = threadIdx.x;
  const int lane = tid & 63, w = tid >> 6;
  const int q = lane >> 4, cn = lane & 15;
  const int m0 = (w & 1) * 16, nh = w >> 1;

  short8 af[8];
  #pragma unroll
  for (int ks = 0; ks < 8; ks++)
    af[ks] = *(const short8*)&e1[(size_t)(tok0 + m0 + cn)*256 + ks*32 + q*8];

  #pragma unroll
  for (int nt = 0; nt < 4; nt++){
    const int n0 = (nh*4 + nt) * 16;
    f32x4 acc = {0.f,0.f,0.f,0.f};
    #pragma unroll
    for (int ks = 0; ks < 8; ks++){
      short8 bf = *(const short8*)&w2b[(size_t)(n0 + cn)*256 + ks*32 + q*8];
      acc = MFMA(af[ks], bf, acc);
    }
    float bias = b2[n0 + cn];
    #pragma unroll
    for (int r = 0; r < 4; r++)
      s_val[(m0 + q*4 + r)*129 + n0 + cn] = acc[r] + bias;
  }
  for (int e = tid; e < 32*32; e += 256){
    int t = e >> 5, k = e & 31;
    float v = 0.f;
    if (k < EMBD){ int a = pact[tok0 + t]; v = emb[(size_t)a*EMBD + k]; }
    s_a[t*168 + 128 + k] = f2bf(v);
  }
  __syncthreads();

  for (int t = w*8; t < w*8 + 8; t++){
    float v0 = s_val[t*129 + lane], v1 = s_val[t*129 + lane + 64];
    float m = wsum(v0+v1) * (1.f/128.f);
    float d0=v0-m, d1=v1-m;
    float var = wsum(d0*d0+d1*d1) * (1.f/128.f);
    if (lane == 0){ s_mr[t][0] = m; s_mr[t][1] = rsqrtf(var + 1e-5f); }
  }
  __syncthreads();
  for (int e = tid; e < 32*128; e += 256){
    int t = e >> 7, c = e & 127;
    float v = (s_val[t*129 + c] - s_mr[t][0]) * s_mr[t][1] * g2[c] + bb2[c];
    s_a[t*168 + c] = f2bf(v);
  }
  __syncthreads();

  short8 af2[5];
  #pragma unroll
  for (int ks = 0; ks < 5; ks++)
    af2[ks] = *(const short8*)&s_a[(m0 + cn)*168 + ks*32 + q*8];

  #pragma unroll
  for (int nt = 0; nt < 4; nt++){
    const int n0 = (nh*4 + nt) * 16;
    f32x4 acc = {0.f,0.f,0.f,0.f};
    #pragma unroll
    for (int ks = 0; ks < 5; ks++){
      short8 bf = *(const short8*)&pwb[(size_t)(n0 + cn)*160 + ks*32 + q*8];
      acc = MFMA(af2[ks], bf, acc);
    }
    float bias = pb[n0 + cn];
    #pragma unroll
    for (int r = 0; r < 4; r++)
      s_val[(m0 + q*4 + r)*129 + n0 + cn] = acc[r] + bias;
  }
  __syncthreads();

  for (int t = w*8; t < w*8 + 8; t++){
    float v0 = s_val[t*129 + lane], v1 = s_val[t*129 + lane + 64];
    float m = wsum(v0+v1) * (1.f/128.f);
    float d0=v0-m, d1=v1-m;
    float var = wsum(d0*d0+d1*d1) * (1.f/128.f);
    if (lane == 0){ s_mr[t][0] = m; s_mr[t][1] = rsqrtf(var + 1e-5f); }
  }
  __syncthreads();
  for (int e = tid; e < 32*128; e += 256){
    int t = e >> 7, c = e & 127;
    float v = (s_val[t*129 + c] - s_mr[t][0]) * s_mr[t][1] * pg[c] + pbb[c];
    X[(size_t)tok0*128 + e] = silu_f(v);
  }
}

// ----- k_pre: xn=LN(x); [x_in,z]=xn@wig.T; dt=softplus(x_in@wdt.T+bdt); bt,ct -----
__global__ __launch_bounds__(256) void k_pre(
    const float* __restrict__ X,
    const float* __restrict__ lng, const float* __restrict__ lnb,
    const ushort_t* __restrict__ wigb, const ushort_t* __restrict__ wdbcb,
    const float* __restrict__ bdt,
    float* __restrict__ XIN, float* __restrict__ Z, float* __restrict__ DT,
    float* __restrict__ BT, float* __restrict__ CT)
{
  __shared__ float s_val[32*129];
  __shared__ ushort_t s_a[32*136];
  __shared__ ushort_t s_xin[32*136];
  __shared__ float s_mr[32][2];
  const int tok0 = blockIdx.x * 32;
  const int tid = threadIdx.x;
  const int lane = tid & 63, w = tid >> 6;
  const int q = lane >> 4, cn = lane & 15;
  const int m0 = (w & 1) * 16, nh = w >> 1;

  for (int e = tid; e < 32*128; e += 256){
    int t = e >> 7, c = e & 127;
    s_val[t*129 + c] = X[(size_t)tok0*128 + e];
  }
  __syncthreads();

  for (int t = w*8; t < w*8 + 8; t++){
    float v0 = s_val[t*129 + lane], v1 = s_val[t*129 + lane + 64];
    float m = wsum(v0+v1) * (1.f/128.f);
    float d0=v0-m, d1=v1-m;
    float var = wsum(d0*d0+d1*d1) * (1.f/128.f);
    if (lane == 0){ s_mr[t][0] = m; s_mr[t][1] = rsqrtf(var + 1e-5f); }
  }
  __syncthreads();
  for (int e = tid; e < 32*128; e += 256){
    int t = e >> 7, c = e & 127;
    float v = (s_val[t*129 + c] - s_mr[t][0]) * s_mr[t][1] * lng[c] + lnb[c];
    s_a[t*136 + c] = f2bf(v);
  }
  __syncthreads();

  short8 af[4];
  #pragma unroll
  for (int ks = 0; ks < 4; ks++)
    af[ks] = *(const short8*)&s_a[(m0 + cn)*136 + ks*32 + q*8];

  #pragma unroll
  for (int nt = 0; nt < 8; nt++){
    const int n0 = (nh*8 + nt) * 16;
    f32x4 acc = {0.f,0.f,0.f,0.f};
    #pragma unroll
    for (int ks = 0; ks < 4; ks++){
      short8 bf = *(const short8*)&wigb[(size_t)(n0 + cn)*128 + ks*32 + q*8];
      acc = MFMA(af[ks], bf, acc);
    }
    if (n0 < 128){
      #pragma unroll
      for (int r = 0; r < 4; r++){
        int tr = m0 + q*4 + r;
        XIN[(size_t)(tok0 + tr)*128 + n0 + cn] = acc[r];
        s_xin[tr*136 + n0 + cn] = f2bf(acc[r]);
      }
    } else {
      #pragma unroll
      for (int r = 0; r < 4; r++){
        int tr = m0 + q*4 + r;
        Z[(size_t)(tok0 + tr)*128 + (n0 - 128) + cn] = acc[r];
      }
    }
  }
  __syncthreads();

  short8 af2[4];
  #pragma unroll
  for (int ks = 0; ks < 4; ks++)
    af2[ks] = *(const short8*)&s_xin[(m0 + cn)*136 + ks*32 + q*8];

  for (int nt = nh; nt < 9; nt += 2){
    const int n0 = nt * 16;
    f32x4 acc = {0.f,0.f,0.f,0.f};
    #pragma unroll
    for (int ks = 0; ks < 4; ks++){
      short8 bf = *(const short8*)&wdbcb[(size_t)(n0 + cn)*128 + ks*32 + q*8];
      acc = MFMA(af2[ks], bf, acc);
    }
    const int col = n0 + cn;
    if (col < 128){
      float bd = bdt[col];
      #pragma unroll
      for (int r = 0; r < 4; r++)
        DT[(size_t)(tok0 + m0 + q*4 + r)*128 + col] = softplus_f(acc[r] + bd);
    } else if (col < 136){
      #pragma unroll
      for (int r = 0; r < 4; r++)
        BT[(size_t)(tok0 + m0 + q*4 + r)*8 + (col - 128)] = acc[r];
    } else {
      #pragma unroll
      for (int r = 0; r < 4; r++)
        CT[(size_t)(tok0 + m0 + q*4 + r)*8 + (col - 136)] = acc[r];
    }
  }
}

// ---- k_scan1: per-segment local h-scan (h_start=0); emit h_loc, P=prod(dA) ----
__global__ __launch_bounds__(128) void k_scan1(
    const float* __restrict__ DT, const float* __restrict__ XIN,
    const float* __restrict__ BT, const float* __restrict__ alog,
    float* __restrict__ HLOC, float* __restrict__ PPR)
{
  __shared__ float4 s_bt[TSEG*2];
  const int b  = blockIdx.x >> 3;
  const int sg = blockIdx.x & 7;
  const int d  = threadIdx.x;      // 0..127
  const int t0 = sg * TSEG;

  s_bt[d] = ((const float4*)(BT + ((size_t)b*TT + t0)*8))[d];

  float A2[8], h[8], p[8];
  #pragma unroll
  for (int s = 0; s < 8; s++){
    A2[s] = -__expf(alog[d*8 + s]) * 1.44269504f;
    h[s] = 0.f; p[s] = 1.f;
  }
  __syncthreads();

  const float* dtp = DT  + ((size_t)b*TT + t0)*128 + d;
  const float* xip = XIN + ((size_t)b*TT + t0)*128 + d;

  float rdt[8], rxi[8], ndt[8], nxi[8];
  #pragma unroll
  for (int r = 0; r < 8; r++){ rdt[r] = dtp[r*128]; rxi[r] = xip[r*128]; }

  for (int c = 0; c < TSEG/8; c++){
    if (c + 1 < TSEG/8){
      #pragma unroll
      for (int r = 0; r < 8; r++){
        ndt[r] = dtp[((c+1)*8 + r)*128];
        nxi[r] = xip[((c+1)*8 + r)*128];
      }
    }
    #pragma unroll
    for (int r = 0; r < 8; r++){
      const int t = c*8 + r;
      float dt = rdt[r];
      float wv = dt * rxi[r];
      float4 b0 = s_bt[t*2], b1 = s_bt[t*2+1];
      float btv[8] = {b0.x,b0.y,b0.z,b0.w,b1.x,b1.y,b1.z,b1.w};
      #pragma unroll
      for (int s = 0; s < 8; s++){
        float dA = exp2f(dt * A2[s]);
        h[s] = fmaf(dA, h[s], wv * btv[s]);
        p[s] *= dA;
      }
    }
    if (c + 1 < TSEG/8){
      #pragma unroll
      for (int r = 0; r < 8; r++){ rdt[r] = ndt[r]; rxi[r] = nxi[r]; }
    }
  }
  const size_t o = (((size_t)b*SSEG + sg)*128 + d)*8;
  #pragma unroll
  for (int s = 0; s < 8; s++){ HLOC[o+s] = h[s]; PPR[o+s] = p[s]; }
}

// ---- k_carry: H_start(0)=h0; H_start(s+1)=h_loc(s)+P(s)*H_start(s) ----
__global__ __launch_bounds__(256) void k_carry(
    const float* __restrict__ h0,
    const float* __restrict__ HLOC, const float* __restrict__ PPR,
    float* __restrict__ HST)
{
  const int b = blockIdx.x;
  const int qd = threadIdx.x;          // 4 slots each of 1024
  float4 H = *(const float4*)(h0 + (size_t)b*1024 + qd*4);
  const size_t hb = (size_t)b*SSEG*1024 + qd*4;
  *(float4*)(HST + hb) = H;
  for (int sg = 0; sg < SSEG-1; sg++){
    float4 hl = *(const float4*)(HLOC + hb + (size_t)sg*1024);
    float4 pp = *(const float4*)(PPR  + hb + (size_t)sg*1024);
    H.x = hl.x + pp.x*H.x; H.y = hl.y + pp.y*H.y;
    H.z = hl.z + pp.z*H.z; H.w = hl.w + pp.w*H.w;
    *(float4*)(HST + hb + (size_t)(sg+1)*1024) = H;
  }
}

// ---- k_scan2: full per-segment scan from H_start; y = sum_s h*c -> Y ----
__global__ __launch_bounds__(128) void k_scan2(
    const float* DT, const float* __restrict__ XIN,
    const float* __restrict__ BT, const float* __restrict__ CT,
    const float* __restrict__ alog, const float* __restrict__ HST,
    float* Y)
{
  __shared__ float4 s_bt[TSEG*2];
  __shared__ float4 s_ct[TSEG*2];
  const int b  = blockIdx.x >> 3;
  const int sg = blockIdx.x & 7;
  const int d  = threadIdx.x;
  const int t0 = sg * TSEG;

  s_bt[d] = ((const float4*)(BT + ((size_t)b*TT + t0)*8))[d];
  s_ct[d] = ((const float4*)(CT + ((size_t)b*TT + t0)*8))[d];

  float A2[8], h[8];
  const size_t ho = (((size_t)b*SSEG + sg)*128 + d)*8;
  #pragma unroll
  for (int s = 0; s < 8; s++){
    A2[s] = -__expf(alog[d*8 + s]) * 1.44269504f;
    h[s] = HST[ho + s];
  }
  __syncthreads();

  const float* dtp = DT  + ((size_t)b*TT + t0)*128 + d;
  const float* xip = XIN + ((size_t)b*TT + t0)*128 + d;
  float* yp = Y + ((size_t)b*TT + t0)*128 + d;

  float rdt[8], rxi[8], ndt[8], nxi[8];
  #pragma unroll
  for (int r = 0; r < 8; r++){ rdt[r] = dtp[r*128]; rxi[r] = xip[r*128]; }

  for (int c = 0; c < TSEG/8; c++){
    if (c + 1 < TSEG/8){
      #pragma unroll
      for (int r = 0; r < 8; r++){
        ndt[r] = dtp[((c+1)*8 + r)*128];
        nxi[r] = xip[((c+1)*8 + r)*128];
      }
    }
    #pragma unroll
    for (int r = 0; r < 8; r++){
      const int t = c*8 + r;
      float dt = rdt[r];
      float wv = dt * rxi[r];
      float4 b0 = s_bt[t*2], b1 = s_bt[t*2+1];
      float4 c0 = s_ct[t*2], c1 = s_ct[t*2+1];
      float btv[8] = {b0.x,b0.y,b0.z,b0.w,b1.x,b1.y,b1.z,b1.w};
      float ctv[8] = {c0.x,c0.y,c0.z,c0.w,c1.x,c1.y,c1.z,c1.w};
      float y = 0.f;
      #pragma unroll
      for (int s = 0; s < 8; s++){
        float dA = exp2f(dt * A2[s]);
        h[s] = fmaf(dA, h[s], wv * btv[s]);
        y = fmaf(h[s], ctv[s], y);
      }
      yp[t*128] = y;
    }
    if (c + 1 < TSEG/8){
      #pragma unroll
      for (int r = 0; r < 8; r++){ rdt[r] = ndt[r]; rxi[r] = nxi[r]; }
    }
  }
}

// ------- k_post: X += (y*silu(z) + x_in*d) @ w_out.T -------
__global__ __launch_bounds__(256) void k_post(
    float* __restrict__ X,
    const float* __restrict__ Y, const float* __restrict__ Z,
    const float* __restrict__ XIN,
    const float* __restrict__ dpar, const ushort_t* __restrict__ woutb)
{
  __shared__ ushort_t s_a[32*136];
  const int tok0 = blockIdx.x * 32;
  const int tid = threadIdx.x;
  const int lane = tid & 63, w = tid >> 6;
  const int q = lane >> 4, cn = lane & 15;
  const int m0 = (w & 1) * 16, nh = w >> 1;

  for (int e = tid; e < 32*128; e += 256){
    int t = e >> 7, c = e & 127;
    size_t g = (size_t)tok0*128 + e;
    float ssm = Y[g]*silu_f(Z[g]) + XIN[g]*dpar[c];
    s_a[t*136 + c] = f2bf(ssm);
  }
  __syncthreads();

  short8 af[4];
  #pragma unroll
  for (int ks = 0; ks < 4; ks++)
    af[ks] = *(const short8*)&s_a[(m0 + cn)*136 + ks*32 + q*8];

  #pragma unroll
  for (int nt = 0; nt < 4; nt++){
    const int n0 = (nh*4 + nt) * 16;
    f32x4 acc = {0.f,0.f,0.f,0.f};
    #pragma unroll
    for (int ks = 0; ks < 4; ks++){
      short8 bf = *(const short8*)&woutb[(size_t)(n0 + cn)*128 + ks*32 + q*8];
      acc = MFMA(af[ks], bf, acc);
    }
    #pragma unroll
    for (int r = 0; r < 4; r++){
      size_t g = (size_t)(tok0 + m0 + q*4 + r)*128 + n0 + cn;
      X[g] += acc[r];
    }
  }
}

// ------- k_head: LN(fn); p=silu(LN(x@pw1.T+pb1)); out=p@pw2.T+pb2 -------
__global__ __launch_bounds__(256) void k_head(
    const float* __restrict__ X,
    const float* __restrict__ fng, const float* __restrict__ fnb,
    const ushort_t* __restrict__ pw1b, const float* __restrict__ pb1,
    const float* __restrict__ pg, const float* __restrict__ pbb,
    const ushort_t* __restrict__ pw2b, const float* __restrict__ pb2,
    float* __restrict__ out)
{
  __shared__ float s_val[32*129];
  __shared__ ushort_t s_a[32*136];
  __shared__ float s_mr[32][2];
  const int tok0 = blockIdx.x * 32;
  const int tid = threadIdx.x;
  const int lane = tid & 63, w = tid >> 6;
  const int q = lane >> 4, cn = lane & 15;
  const int m0 = (w & 1) * 16, nh = w >> 1;

  for (int e = tid; e < 32*128; e += 256){
    int t = e >> 7, c = e & 127;
    s_val[t*129 + c] = X[(size_t)tok0*128 + e];
  }
  __syncthreads();

  for (int t = w*8; t < w*8 + 8; t++){
    float v0 = s_val[t*129 + lane], v1 = s_val[t*129 + lane + 64];
    float m = wsum(v0+v1) * (1.f/128.f);
    float d0=v0-m, d1=v1-m;
    float var = wsum(d0*d0+d1*d1) * (1.f/128.f);
    if (lane == 0){ s_mr[t][0] = m; s_mr[t][1] = rsqrtf(var + 1e-5f); }
  }
  __syncthreads();
  for (int e = tid; e < 32*128; e += 256){
    int t = e >> 7, c = e & 127;
    float v = (s_val[t*129 + c] - s_mr[t][0]) * s_mr[t][1] * fng[c] + fnb[c];
    s_a[t*136 + c] = f2bf(v);
  }
  __syncthreads();

  short8 af[4];
  #pragma unroll
  for (int ks = 0; ks < 4; ks++)
    af[ks] = *(const short8*)&s_a[(m0 + cn)*136 + ks*32 + q*8];

  #pragma unroll
  for (int nt = 0; nt < 4; nt++){
    const int n0 = (nh*4 + nt) * 16;
    f32x4 acc = {0.f,0.f,0.f,0.f};
    #pragma unroll
    for (int ks = 0; ks < 4; ks++){
      short8 bf = *(const short8*)&pw1b[(size_t)(n0 + cn)*128 + ks*32 + q*8];
      acc = MFMA(af[ks], bf, acc);
    }
    float bias = pb1[n0 + cn];
    #pragma unroll
    for (int r = 0; r < 4; r++)
      s_val[(m0 + q*4 + r)*129 + n0 + cn] = acc[r] + bias;
  }
  __syncthreads();

  for (int t = w*8; t < w*8 + 8; t++){
    float v0 = s_val[t*129 + lane], v1 = s_val[t*129 + lane + 64];
    float m = wsum(v0+v1) * (1.f/128.f);
    float d0=v0-m, d1=v1-m;
    float var = wsum(d0*d0+d1*d1) * (1.f/128.f);
    if (lane == 0){ s_mr[t][0] = m; s_mr[t][1] = rsqrtf(var + 1e-5f); }
  }
  __syncthreads();
  for (int e = tid; e < 32*128; e += 256){
    int t = e >> 7, c = e & 127;
    float v = (s_val[t*129 + c] - s_mr[t][0]) * s_mr[t][1] * pg[c] + pbb[c];
    s_a[t*136 + c] = f2bf(silu_f(v));
  }
  __syncthreads();

  short8 af2[4];
  #pragma unroll
  for (int ks = 0; ks < 4; ks++)
    af2[ks] = *(const short8*)&s_a[(m0 + cn)*136 + ks*32 + q*8];

  {
    const int n0 = nh * 16;
    f32x4 acc = {0.f,0.f,0.f,0.f};
    #pragma unroll
    for (int ks = 0; ks < 4; ks++){
      short8 bf = *(const short8*)&pw2b[(size_t)(n0 + cn)*128 + ks*32 + q*8];
      acc = MFMA(af2[ks], bf, acc);
    }
    const int col = n0 + cn;
    if (col < NAD){
      float bias = pb2[col];
      #pragma unroll
      for (int r = 0; r < 4; r++)
        out[(size_t)(tok0 + m0 + q*4 + r)*NAD + col] = acc[r] + bias;
    }
  }
}

extern "C" void kernel_launch(void* const* d_in, const int* in_sizes, int n_in,
                              void* d_out, int out_size, void* d_ws, size_t ws_size,
                              hipStream_t stream) {
  const float* obs    = (const float*)d_in[0];
  const float* h0     = (const float*)d_in[1];
  const float* enc_w1 = (const float*)d_in[2];
  const float* enc_b1 = (const float*)d_in[3];
  const float* enc_g1 = (const float*)d_in[4];
  const float* enc_bb1= (const float*)d_in[5];
  const float* enc_w2 = (const float*)d_in[6];
  const float* enc_b2 = (const float*)d_in[7];
  const float* enc_g2 = (const float*)d_in[8];
  const float* enc_bb2= (const float*)d_in[9];
  const float* emb    = (const float*)d_in[10];
  const float* proj_w = (const float*)d_in[11];
  const float* proj_b = (const float*)d_in[12];
  const float* proj_g = (const float*)d_in[13];
  const float* proj_bb= (const float*)d_in[14];
  const float* m_ln_g = (const float*)d_in[15];
  const float* m_ln_b = (const float*)d_in[16];
  const float* m_w_ig = (const float*)d_in[17];
  const float* m_w_dt = (const float*)d_in[18];
  const float* m_b_dt = (const float*)d_in[19];
  const float* m_a_log= (const float*)d_in[20];
  const float* m_w_b  = (const float*)d_in[21];
  const float* m_w_c  = (const float*)d_in[22];
  const float* m_d    = (const float*)d_in[23];
  const float* m_w_out= (const float*)d_in[24];
  const float* fn_g   = (const float*)d_in[25];
  const float* fn_b   = (const float*)d_in[26];
  const float* pol_w1 = (const float*)d_in[27];
  const float* pol_b1 = (const float*)d_in[28];
  const float* pol_g  = (const float*)d_in[29];
  const float* pol_bb = (const float*)d_in[30];
  const float* pol_w2 = (const float*)d_in[31];
  const float* pol_b2 = (const float*)d_in[32];
  const int*   pact   = (const int*)d_in[33];

  float* ws  = (float*)d_ws;
  float* X   = ws;
  float* XIN = X   + (size_t)NTOK*128;
  float* Z   = XIN + (size_t)NTOK*128;
  float* DT  = Z   + (size_t)NTOK*128;
  float* BT  = DT  + (size_t)NTOK*128;
  float* CT  = BT  + (size_t)NTOK*8;
  float* Y   = DT;                          // scan2 overwrites DT in place
  ushort_t* E1 = (ushort_t*)XIN;            // bf16 [NTOK][256]

  ushort_t* W1B   = (ushort_t*)(CT + (size_t)NTOK*8);
  ushort_t* W2B   = W1B   + 256*128;
  ushort_t* PWB   = W2B   + 128*256;
  ushort_t* WIGB  = PWB   + 128*160;
  ushort_t* WDBCB = WIGB  + 3*256*128;
  ushort_t* WOUTB = WDBCB + 3*144*128;
  ushort_t* PW1B  = WOUTB + 3*128*128;
  ushort_t* PW2B  = PW1B  + 128*128;
  float* HLOC = (float*)(PW2B + 32*128);    // [B][SSEG][128][8]
  float* PPR  = HLOC + (size_t)BB*SSEG*1024;
  float* HST  = PPR  + (size_t)BB*SSEG*1024;

  PJobs P;
  int nj = 0;
  auto add = [&](const float* src, ushort_t* dst, int N, int K, int Kpad, int rowofs, int Nw){
    P.j[nj].src = src; P.j[nj].dst = dst; P.j[nj].N = N; P.j[nj].K = K;
    P.j[nj].Kpad = Kpad; P.j[nj].rowofs = rowofs; P.j[nj].Nw = Nw; nj++;
  };
  add(enc_w1, W1B, 256, 115, 128, 0, 256);
  add(enc_w2, W2B, 128, 256, 256, 0, 128);
  add(proj_w, PWB, 128, 144, 160, 0, 128);
  for (int l = 0; l < NLD; l++)
    add(m_w_ig + (size_t)l*256*128, WIGB + (size_t)l*256*128, 256, 128, 128, 0, 256);
  for (int l = 0; l < NLD; l++){
    add(m_w_dt + (size_t)l*128*128, WDBCB + (size_t)l*144*128, 128, 128, 128, 0,   128);
    add(m_w_b  + (size_t)l*8*128,   WDBCB + (size_t)l*144*128,   8, 128, 128, 128,   8);
    add(m_w_c  + (size_t)l*8*128,   WDBCB + (size_t)l*144*128,   8, 128, 128, 136,   8);
  }
  for (int l = 0; l < NLD; l++)
    add(m_w_out + (size_t)l*128*128, WOUTB + (size_t)l*128*128, 128, 128, 128, 0, 128);
  add(pol_w1, PW1B, 128, 128, 128, 0, 128);
  add(pol_w2, PW2B,  19, 128, 128, 0,  32);

  const int nblk = NTOK/32;  // 1024

  k_prep<<<20*4, 256, 0, stream>>>(P);
  k_enc1<<<nblk, 256, 0, stream>>>(obs, W1B, enc_b1, enc_g1, enc_bb1, E1);
  k_enc2<<<nblk, 256, 0, stream>>>(E1, W2B, enc_b2, enc_g2, enc_bb2,
                                   emb, pact, PWB, proj_b, proj_g, proj_bb, X);
  for (int l = 0; l < NLD; l++){
    k_pre<<<nblk, 256, 0, stream>>>(X,
        m_ln_g + l*128, m_ln_b + l*128,
        WIGB + (size_t)l*256*128, WDBCB + (size_t)l*144*128, m_b_dt + l*128,
        XIN, Z, DT, BT, CT);
    k_scan1<<<BB*SSEG, 128, 0, stream>>>(DT, XIN, BT,
        m_a_log + (size_t)l*DMD*DSD, HLOC, PPR);
    k_carry<<<BB, 256, 0, stream>>>(h0 + (size_t)l*BB*DMD*DSD, HLOC, PPR, HST);
    k_scan2<<<BB*SSEG, 128, 0, stream>>>(DT, XIN, BT, CT,
        m_a_log + (size_t)l*DMD*DSD, HST, Y);
    k_post<<<nblk, 256, 0, stream>>>(X, Y, Z, XIN,
        m_d + l*128, WOUTB + (size_t)l*128*128);
  }
  k_head<<<nblk, 256, 0, stream>>>(X, fn_g, fn_b, PW1B, pol_b1,
                                   pol_g, pol_bb, PW2B, pol_b2, (float*)d_out);
}

// Round 6
// 449.561 us; speedup vs baseline: 3.3884x; 1.2211x over previous
//
#include <hip/hip_runtime.h>
#include <math.h>

#define BB 64
#define TT 512
#define OBSD 115
#define DMD 128
#define DSD 8
#define NLD 3
#define EMBD 16
#define NAD 19
#define H1D 256
#define NTOK (BB*TT)
#define SSEG 8
#define TSEG (TT/SSEG)   // 64

typedef unsigned short ushort_t;
typedef __attribute__((ext_vector_type(8))) short short8;
typedef __attribute__((ext_vector_type(4))) float f32x4;

__device__ __forceinline__ float wsum(float v){
  #pragma unroll
  for (int o = 1; o < 64; o <<= 1) v += __shfl_xor(v, o, 64);
  return v;
}
__device__ __forceinline__ float silu_f(float x){ return x / (1.f + __expf(-x)); }
__device__ __forceinline__ float softplus_f(float x){
  return fmaxf(x, 0.f) + log1pf(__expf(-fabsf(x)));
}
__device__ __forceinline__ ushort_t f2bf(float x){
  unsigned u = __float_as_uint(x);
  unsigned r = (u + 0x7fffu + ((u >> 16) & 1u)) >> 16;
  return (ushort_t)r;
}
__device__ __forceinline__ float b2f(ushort_t x){
  return __uint_as_float(((unsigned)x) << 16);
}
#define MFMA(a,b,c) __builtin_amdgcn_mfma_f32_16x16x32_bf16((a),(b),(c),0,0,0)

// ---------------- k_prep: fp32 weights -> padded bf16 [Nrow][Kpad] ----------------
struct PJob { const float* src; ushort_t* dst; int N; int K; int Kpad; int rowofs; int Nw; };
struct PJobs { PJob j[20]; };

__global__ __launch_bounds__(256) void k_prep(PJobs P){
  const int job = blockIdx.x >> 2;
  const int sub = blockIdx.x & 3;
  PJob pj = P.j[job];
  const int elems = pj.Nw * pj.Kpad;
  for (int idx = sub*256 + threadIdx.x; idx < elems; idx += 4*256){
    int n = idx / pj.Kpad;
    int k = idx - n*pj.Kpad;
    float v = (n < pj.N && k < pj.K) ? pj.src[(size_t)n*pj.K + k] : 0.f;
    pj.dst[(size_t)(pj.rowofs + n)*pj.Kpad + k] = f2bf(v);
  }
}

// ---------------- k_enc1: e1(bf16) = silu(LN(obs @ w1.T + b1)) ----------------
__global__ __launch_bounds__(256) void k_enc1(
    const float* __restrict__ obs, const ushort_t* __restrict__ w1b,
    const float* __restrict__ b1, const float* __restrict__ g1,
    const float* __restrict__ bb1, ushort_t* __restrict__ e1)
{
  __shared__ ushort_t s_a[32*136];
  __shared__ float s_val[32*257];
  __shared__ float s_mr[32][2];
  const int tok0 = blockIdx.x * 32;
  const int tid = threadIdx.x;
  const int lane = tid & 63, w = tid >> 6;
  const int q = lane >> 4, cn = lane & 15;
  const int m0 = (w & 1) * 16, nh = w >> 1;

  for (int e = tid; e < 32*16; e += 256){
    int t = e >> 4, kc = e & 15;
    const float* op = obs + (size_t)(tok0 + t)*OBSD;
    short8 v;
    #pragma unroll
    for (int j = 0; j < 8; j++){
      int k = kc*8 + j;
      v[j] = (short)f2bf(k < OBSD ? op[k] : 0.f);
    }
    *(short8*)&s_a[t*136 + kc*8] = v;
  }
  __syncthreads();

  short8 af[4];
  #pragma unroll
  for (int ks = 0; ks < 4; ks++)
    af[ks] = *(const short8*)&s_a[(m0 + cn)*136 + ks*32 + q*8];

  #pragma unroll
  for (int nt = 0; nt < 8; nt++){
    const int n0 = (nh*8 + nt) * 16;
    f32x4 acc = {0.f,0.f,0.f,0.f};
    #pragma unroll
    for (int ks = 0; ks < 4; ks++){
      short8 bf = *(const short8*)&w1b[(size_t)(n0 + cn)*128 + ks*32 + q*8];
      acc = MFMA(af[ks], bf, acc);
    }
    float bias = b1[n0 + cn];
    #pragma unroll
    for (int r = 0; r < 4; r++)
      s_val[(m0 + q*4 + r)*257 + n0 + cn] = acc[r] + bias;
  }
  __syncthreads();

  for (int t = w*8; t < w*8 + 8; t++){
    float v0 = s_val[t*257 + lane],     v1 = s_val[t*257 + lane + 64];
    float v2 = s_val[t*257 + lane+128], v3 = s_val[t*257 + lane + 192];
    float m = wsum(v0+v1+v2+v3) * (1.f/256.f);
    float d0=v0-m, d1=v1-m, d2=v2-m, d3=v3-m;
    float var = wsum(d0*d0+d1*d1+d2*d2+d3*d3) * (1.f/256.f);
    if (lane == 0){ s_mr[t][0] = m; s_mr[t][1] = rsqrtf(var + 1e-5f); }
  }
  __syncthreads();
  for (int e = tid; e < 32*256; e += 256){
    int t = e >> 8, c = e & 255;
    float v = (s_val[t*257 + c] - s_mr[t][0]) * s_mr[t][1] * g1[c] + bb1[c];
    e1[(size_t)(tok0 + t)*256 + c] = f2bf(silu_f(v));
  }
}

// ------- k_enc2p: enc2 + proj + LN(l0) + pre(l0) fused (32 tok, 256 thr) -------
__global__ __launch_bounds__(256) void k_enc2p(
    const ushort_t* __restrict__ e1, const ushort_t* __restrict__ w2b,
    const float* __restrict__ b2, const float* __restrict__ g2,
    const float* __restrict__ bb2,
    const float* __restrict__ emb, const int* __restrict__ pact,
    const ushort_t* __restrict__ pwb, const float* __restrict__ pb,
    const float* __restrict__ pg, const float* __restrict__ pbb,
    float* __restrict__ X,
    const float* __restrict__ lng, const float* __restrict__ lnb,
    const ushort_t* __restrict__ wigb, const ushort_t* __restrict__ wdbcb,
    const float* __restrict__ bdt,
    ushort_t* __restrict__ XINo, ushort_t* __restrict__ Zo,
    ushort_t* __restrict__ DTo, float* __restrict__ BTo, float* __restrict__ CTo)
{
  __shared__ float s_val[32*129];
  __shared__ ushort_t s_a[32*168];
  __shared__ ushort_t s_xin[32*136];
  __shared__ float s_mr[32][2];
  const int tok0 = blockIdx.x * 32;
  const int tid = threadIdx.x;
  const int lane = tid & 63, w = tid >> 6;
  const int q = lane >> 4, cn = lane & 15;
  const int m0 = (w & 1) * 16, nh = w >> 1;

  // GEMM1: e1 @ w2.T
  {
    short8 af[8];
    #pragma unroll
    for (int ks = 0; ks < 8; ks++)
      af[ks] = *(const short8*)&e1[(size_t)(tok0 + m0 + cn)*256 + ks*32 + q*8];
    #pragma unroll
    for (int nt = 0; nt < 4; nt++){
      const int n0 = (nh*4 + nt) * 16;
      f32x4 acc = {0.f,0.f,0.f,0.f};
      #pragma unroll
      for (int ks = 0; ks < 8; ks++){
        short8 bf = *(const short8*)&w2b[(size_t)(n0 + cn)*256 + ks*32 + q*8];
        acc = MFMA(af[ks], bf, acc);
      }
      float bias = b2[n0 + cn];
      #pragma unroll
      for (int r = 0; r < 4; r++)
        s_val[(m0 + q*4 + r)*129 + n0 + cn] = acc[r] + bias;
    }
  }
  for (int e = tid; e < 32*32; e += 256){
    int t = e >> 5, k = e & 31;
    float v = 0.f;
    if (k < EMBD){ int a = pact[tok0 + t]; v = emb[(size_t)a*EMBD + k]; }
    s_a[t*168 + 128 + k] = f2bf(v);
  }
  __syncthreads();

  for (int t = w*8; t < w*8 + 8; t++){
    float v0 = s_val[t*129 + lane], v1 = s_val[t*129 + lane + 64];
    float m = wsum(v0+v1) * (1.f/128.f);
    float d0=v0-m, d1=v1-m;
    float var = wsum(d0*d0+d1*d1) * (1.f/128.f);
    if (lane == 0){ s_mr[t][0] = m; s_mr[t][1] = rsqrtf(var + 1e-5f); }
  }
  __syncthreads();
  for (int e = tid; e < 32*128; e += 256){
    int t = e >> 7, c = e & 127;
    float v = (s_val[t*129 + c] - s_mr[t][0]) * s_mr[t][1] * g2[c] + bb2[c];
    s_a[t*168 + c] = f2bf(v);
  }
  __syncthreads();

  // GEMM2: proj (Kpad=160)
  {
    short8 af2[5];
    #pragma unroll
    for (int ks = 0; ks < 5; ks++)
      af2[ks] = *(const short8*)&s_a[(m0 + cn)*168 + ks*32 + q*8];
    #pragma unroll
    for (int nt = 0; nt < 4; nt++){
      const int n0 = (nh*4 + nt) * 16;
      f32x4 acc = {0.f,0.f,0.f,0.f};
      #pragma unroll
      for (int ks = 0; ks < 5; ks++){
        short8 bf = *(const short8*)&pwb[(size_t)(n0 + cn)*160 + ks*32 + q*8];
        acc = MFMA(af2[ks], bf, acc);
      }
      float bias = pb[n0 + cn];
      #pragma unroll
      for (int r = 0; r < 4; r++)
        s_val[(m0 + q*4 + r)*129 + n0 + cn] = acc[r] + bias;
    }
  }
  __syncthreads();

  for (int t = w*8; t < w*8 + 8; t++){
    float v0 = s_val[t*129 + lane], v1 = s_val[t*129 + lane + 64];
    float m = wsum(v0+v1) * (1.f/128.f);
    float d0=v0-m, d1=v1-m;
    float var = wsum(d0*d0+d1*d1) * (1.f/128.f);
    if (lane == 0){ s_mr[t][0] = m; s_mr[t][1] = rsqrtf(var + 1e-5f); }
  }
  __syncthreads();
  // X = silu(LN(...)); keep in s_val, write global
  for (int e = tid; e < 32*128; e += 256){
    int t = e >> 7, c = e & 127;
    float v = (s_val[t*129 + c] - s_mr[t][0]) * s_mr[t][1] * pg[c] + pbb[c];
    v = silu_f(v);
    X[(size_t)tok0*128 + e] = v;
    s_val[t*129 + c] = v;
  }
  __syncthreads();

  // mamba LN (layer 0)
  for (int t = w*8; t < w*8 + 8; t++){
    float v0 = s_val[t*129 + lane], v1 = s_val[t*129 + lane + 64];
    float m = wsum(v0+v1) * (1.f/128.f);
    float d0=v0-m, d1=v1-m;
    float var = wsum(d0*d0+d1*d1) * (1.f/128.f);
    if (lane == 0){ s_mr[t][0] = m; s_mr[t][1] = rsqrtf(var + 1e-5f); }
  }
  __syncthreads();
  for (int e = tid; e < 32*128; e += 256){
    int t = e >> 7, c = e & 127;
    float v = (s_val[t*129 + c] - s_mr[t][0]) * s_mr[t][1] * lng[c] + lnb[c];
    s_a[t*136 + c] = f2bf(v);     // reuse s_a with stride 136
  }
  __syncthreads();

  // GEMM wig: N=256, K=128
  {
    short8 af[4];
    #pragma unroll
    for (int ks = 0; ks < 4; ks++)
      af[ks] = *(const short8*)&s_a[(m0 + cn)*136 + ks*32 + q*8];
    #pragma unroll
    for (int nt = 0; nt < 8; nt++){
      const int n0 = (nh*8 + nt) * 16;
      f32x4 acc = {0.f,0.f,0.f,0.f};
      #pragma unroll
      for (int ks = 0; ks < 4; ks++){
        short8 bf = *(const short8*)&wigb[(size_t)(n0 + cn)*128 + ks*32 + q*8];
        acc = MFMA(af[ks], bf, acc);
      }
      if (n0 < 128){
        #pragma unroll
        for (int r = 0; r < 4; r++){
          int tr = m0 + q*4 + r;
          ushort_t bb = f2bf(acc[r]);
          XINo[(size_t)(tok0 + tr)*128 + n0 + cn] = bb;
          s_xin[tr*136 + n0 + cn] = bb;
        }
      } else {
        #pragma unroll
        for (int r = 0; r < 4; r++){
          int tr = m0 + q*4 + r;
          Zo[(size_t)(tok0 + tr)*128 + (n0 - 128) + cn] = f2bf(acc[r]);
        }
      }
    }
  }
  __syncthreads();

  // GEMM wdbc: 144 rows
  {
    short8 af2[4];
    #pragma unroll
    for (int ks = 0; ks < 4; ks++)
      af2[ks] = *(const short8*)&s_xin[(m0 + cn)*136 + ks*32 + q*8];
    for (int nt = nh; nt < 9; nt += 2){
      const int n0 = nt * 16;
      f32x4 acc = {0.f,0.f,0.f,0.f};
      #pragma unroll
      for (int ks = 0; ks < 4; ks++){
        short8 bf = *(const short8*)&wdbcb[(size_t)(n0 + cn)*128 + ks*32 + q*8];
        acc = MFMA(af2[ks], bf, acc);
      }
      const int col = n0 + cn;
      if (col < 128){
        float bd = bdt[col];
        #pragma unroll
        for (int r = 0; r < 4; r++)
          DTo[(size_t)(tok0 + m0 + q*4 + r)*128 + col] = f2bf(softplus_f(acc[r] + bd));
      } else if (col < 136){
        #pragma unroll
        for (int r = 0; r < 4; r++)
          BTo[(size_t)(tok0 + m0 + q*4 + r)*8 + (col - 128)] = acc[r];
      } else {
        #pragma unroll
        for (int r = 0; r < 4; r++)
          CTo[(size_t)(tok0 + m0 + q*4 + r)*8 + (col - 136)] = acc[r];
      }
    }
  }
}

// ---- k_scan1: per-segment local h-scan (h_start=0); emit h_loc, P=prod(dA) ----
__global__ __launch_bounds__(128) void k_scan1(
    const ushort_t* __restrict__ DTb, const ushort_t* __restrict__ XINb,
    const float* __restrict__ BT, const float* __restrict__ alog,
    float* __restrict__ HLOC, float* __restrict__ PPR)
{
  __shared__ float4 s_bt[TSEG*2];
  const int b  = blockIdx.x >> 3;
  const int sg = blockIdx.x & 7;
  const int d  = threadIdx.x;      // 0..127
  const int t0 = sg * TSEG;

  s_bt[d] = ((const float4*)(BT + ((size_t)b*TT + t0)*8))[d];

  float A2[8], h[8], p[8];
  #pragma unroll
  for (int s = 0; s < 8; s++){
    A2[s] = -__expf(alog[d*8 + s]) * 1.44269504f;
    h[s] = 0.f; p[s] = 1.f;
  }
  __syncthreads();

  const ushort_t* dtp = DTb  + ((size_t)b*TT + t0)*128 + d;
  const ushort_t* xip = XINb + ((size_t)b*TT + t0)*128 + d;

  ushort_t rdt[8], rxi[8], ndt[8], nxi[8];
  #pragma unroll
  for (int r = 0; r < 8; r++){ rdt[r] = dtp[r*128]; rxi[r] = xip[r*128]; }

  for (int c = 0; c < TSEG/8; c++){
    if (c + 1 < TSEG/8){
      #pragma unroll
      for (int r = 0; r < 8; r++){
        ndt[r] = dtp[((c+1)*8 + r)*128];
        nxi[r] = xip[((c+1)*8 + r)*128];
      }
    }
    #pragma unroll
    for (int r = 0; r < 8; r++){
      const int t = c*8 + r;
      float dt = b2f(rdt[r]);
      float wv = dt * b2f(rxi[r]);
      float4 b0 = s_bt[t*2], b1 = s_bt[t*2+1];
      float btv[8] = {b0.x,b0.y,b0.z,b0.w,b1.x,b1.y,b1.z,b1.w};
      #pragma unroll
      for (int s = 0; s < 8; s++){
        float dA = exp2f(dt * A2[s]);
        h[s] = fmaf(dA, h[s], wv * btv[s]);
        p[s] *= dA;
      }
    }
    if (c + 1 < TSEG/8){
      #pragma unroll
      for (int r = 0; r < 8; r++){ rdt[r] = ndt[r]; rxi[r] = nxi[r]; }
    }
  }
  const size_t o = (((size_t)b*SSEG + sg)*128 + d)*8;
  #pragma unroll
  for (int s = 0; s < 8; s++){ HLOC[o+s] = h[s]; PPR[o+s] = p[s]; }
}

// ---- k_carry ----
__global__ __launch_bounds__(256) void k_carry(
    const float* __restrict__ h0,
    const float* __restrict__ HLOC, const float* __restrict__ PPR,
    float* __restrict__ HST)
{
  const int b = blockIdx.x;
  const int qd = threadIdx.x;
  float4 H = *(const float4*)(h0 + (size_t)b*1024 + qd*4);
  const size_t hb = (size_t)b*SSEG*1024 + qd*4;
  *(float4*)(HST + hb) = H;
  for (int sg = 0; sg < SSEG-1; sg++){
    float4 hl = *(const float4*)(HLOC + hb + (size_t)sg*1024);
    float4 pp = *(const float4*)(PPR  + hb + (size_t)sg*1024);
    H.x = hl.x + pp.x*H.x; H.y = hl.y + pp.y*H.y;
    H.z = hl.z + pp.z*H.z; H.w = hl.w + pp.w*H.w;
    *(float4*)(HST + hb + (size_t)(sg+1)*1024) = H;
  }
}

// ======== shared device code for scan + ssm + wout GEMM + X update + LN ========
// block: (b,sg) -> 64 tokens, 128 threads (2 waves).
// After call: s_x holds new X rows (fp32, stride 130), s_mr holds LN stats of s_x.
__device__ __forceinline__ void scan_post_ln(
    const ushort_t* DTb, const ushort_t* XINb, const ushort_t* Zb,
    const float* BT, const float* CT, const float* alog, const float* HST,
    const float* dpar, const ushort_t* woutb, float* X,
    float4* s_bt, float4* s_ct, ushort_t* s_a, float* s_x, float (*s_mr)[2],
    int b, int sg)
{
  const int tid = threadIdx.x;
  const int t0 = sg * TSEG;
  const int d = tid;
  const int lane = tid & 63, w = tid >> 6;
  const int q = lane >> 4, cn = lane & 15;

  s_bt[d] = ((const float4*)(BT + ((size_t)b*TT + t0)*8))[d];
  s_ct[d] = ((const float4*)(CT + ((size_t)b*TT + t0)*8))[d];

  float A2[8], h[8];
  const size_t ho = (((size_t)b*SSEG + sg)*128 + d)*8;
  #pragma unroll
  for (int s = 0; s < 8; s++){
    A2[s] = -__expf(alog[d*8 + s]) * 1.44269504f;
    h[s] = HST[ho + s];
  }
  const float dp = dpar[d];
  __syncthreads();

  const ushort_t* dtp = DTb  + ((size_t)b*TT + t0)*128 + d;
  const ushort_t* xip = XINb + ((size_t)b*TT + t0)*128 + d;
  const ushort_t* zp  = Zb   + ((size_t)b*TT + t0)*128 + d;

  ushort_t rdt[8], rxi[8], rz[8], ndt[8], nxi[8], nz[8];
  #pragma unroll
  for (int r = 0; r < 8; r++){ rdt[r] = dtp[r*128]; rxi[r] = xip[r*128]; rz[r] = zp[r*128]; }

  for (int c = 0; c < TSEG/8; c++){
    if (c + 1 < TSEG/8){
      #pragma unroll
      for (int r = 0; r < 8; r++){
        ndt[r] = dtp[((c+1)*8 + r)*128];
        nxi[r] = xip[((c+1)*8 + r)*128];
        nz[r]  = zp [((c+1)*8 + r)*128];
      }
    }
    #pragma unroll
    for (int r = 0; r < 8; r++){
      const int t = c*8 + r;
      float dt = b2f(rdt[r]);
      float xi = b2f(rxi[r]);
      float wv = dt * xi;
      float4 b0 = s_bt[t*2], b1 = s_bt[t*2+1];
      float4 c0 = s_ct[t*2], c1 = s_ct[t*2+1];
      float btv[8] = {b0.x,b0.y,b0.z,b0.w,b1.x,b1.y,b1.z,b1.w};
      float ctv[8] = {c0.x,c0.y,c0.z,c0.w,c1.x,c1.y,c1.z,c1.w};
      float y = 0.f;
      #pragma unroll
      for (int s = 0; s < 8; s++){
        float dA = exp2f(dt * A2[s]);
        h[s] = fmaf(dA, h[s], wv * btv[s]);
        y = fmaf(h[s], ctv[s], y);
      }
      float ssm = y * silu_f(b2f(rz[r])) + xi * dp;
      s_a[t*136 + d] = f2bf(ssm);
    }
    if (c + 1 < TSEG/8){
      #pragma unroll
      for (int r = 0; r < 8; r++){ rdt[r] = ndt[r]; rxi[r] = nxi[r]; rz[r] = nz[r]; }
    }
  }
  __syncthreads();

  // wout GEMM (64x128 @ 128x128^T) + residual; X new -> global + s_x
  {
    short8 af[4][4];
    #pragma unroll
    for (int mt = 0; mt < 4; mt++)
      #pragma unroll
      for (int ks = 0; ks < 4; ks++)
        af[mt][ks] = *(const short8*)&s_a[(mt*16 + cn)*136 + ks*32 + q*8];

    for (int nt = w; nt < 8; nt += 2){
      const int n0 = nt * 16;
      short8 bf[4];
      #pragma unroll
      for (int ks = 0; ks < 4; ks++)
        bf[ks] = *(const short8*)&woutb[(size_t)(n0 + cn)*128 + ks*32 + q*8];
      #pragma unroll
      for (int mt = 0; mt < 4; mt++){
        f32x4 acc = {0.f,0.f,0.f,0.f};
        #pragma unroll
        for (int ks = 0; ks < 4; ks++) acc = MFMA(af[mt][ks], bf[ks], acc);
        #pragma unroll
        for (int r = 0; r < 4; r++){
          const int tr = mt*16 + q*4 + r;
          const size_t g = ((size_t)b*TT + t0 + tr)*128 + n0 + cn;
          float xn = X[g] + acc[r];
          X[g] = xn;
          s_x[tr*130 + n0 + cn] = xn;
        }
      }
    }
  }
  __syncthreads();

  // LN stats over s_x rows (2 threads per token)
  {
    const int t = tid >> 1, hf = tid & 1;
    float s = 0.f, s2 = 0.f;
    const float* row = s_x + t*130 + hf*64;
    for (int j = 0; j < 64; j++){ float v = row[j]; s += v; s2 = fmaf(v, v, s2); }
    s  += __shfl_xor(s, 1, 64);
    s2 += __shfl_xor(s2, 1, 64);
    float m = s * (1.f/128.f);
    float var = s2 * (1.f/128.f) - m*m;
    if (hf == 0){ s_mr[t][0] = m; s_mr[t][1] = rsqrtf(var + 1e-5f); }
  }
  __syncthreads();
}

// ---- k_scan2p: scan(l)+post(l)+LN(l+1)+pre(l+1) ----
__global__ __launch_bounds__(128) void k_scan2p(
    const ushort_t* DTb, const ushort_t* XINb, const ushort_t* Zb,
    const float* __restrict__ BT, const float* __restrict__ CT,
    const float* __restrict__ alog, const float* __restrict__ HST,
    const float* __restrict__ dpar, const ushort_t* __restrict__ woutb,
    float* __restrict__ X,
    const float* __restrict__ lng, const float* __restrict__ lnb,
    const ushort_t* __restrict__ wigb, const ushort_t* __restrict__ wdbcb,
    const float* __restrict__ bdt,
    ushort_t* DToo, ushort_t* XINoo, ushort_t* Zoo,
    float* __restrict__ BTo, float* __restrict__ CTo)
{
  __shared__ float4 s_bt[TSEG*2];
  __shared__ float4 s_ct[TSEG*2];
  __shared__ ushort_t s_a[64*136];
  __shared__ float s_x[64*130];
  __shared__ float s_mr[64][2];

  const int b  = blockIdx.x >> 3;
  const int sg = blockIdx.x & 7;
  const int t0 = sg * TSEG;
  const int tid = threadIdx.x;
  const int lane = tid & 63, w = tid >> 6;
  const int q = lane >> 4, cn = lane & 15;

  scan_post_ln(DTb, XINb, Zb, BT, CT, alog, HST, dpar, woutb, X,
               s_bt, s_ct, s_a, s_x, s_mr, b, sg);

  // normalize -> s_a bf16 (thread tid owns column tid)
  {
    float g = lng[tid], c = lnb[tid];
    for (int t = 0; t < 64; t++){
      float v = (s_x[t*130 + tid] - s_mr[t][0]) * s_mr[t][1] * g + c;
      s_a[t*136 + tid] = f2bf(v);
    }
  }
  __syncthreads();

  ushort_t* s_xin = (ushort_t*)s_x;   // reuse as bf16 [64][136]

  // GEMM wig: N=256, K=128
  {
    short8 af[4][4];
    #pragma unroll
    for (int mt = 0; mt < 4; mt++)
      #pragma unroll
      for (int ks = 0; ks < 4; ks++)
        af[mt][ks] = *(const short8*)&s_a[(mt*16 + cn)*136 + ks*32 + q*8];

    for (int nt = w; nt < 16; nt += 2){
      const int n0 = nt * 16;
      short8 bf[4];
      #pragma unroll
      for (int ks = 0; ks < 4; ks++)
        bf[ks] = *(const short8*)&wigb[(size_t)(n0 + cn)*128 + ks*32 + q*8];
      #pragma unroll
      for (int mt = 0; mt < 4; mt++){
        f32x4 acc = {0.f,0.f,0.f,0.f};
        #pragma unroll
        for (int ks = 0; ks < 4; ks++) acc = MFMA(af[mt][ks], bf[ks], acc);
        if (n0 < 128){
          #pragma unroll
          for (int r = 0; r < 4; r++){
            const int tr = mt*16 + q*4 + r;
            ushort_t bb = f2bf(acc[r]);
            XINoo[((size_t)b*TT + t0 + tr)*128 + n0 + cn] = bb;
            s_xin[tr*136 + n0 + cn] = bb;
          }
        } else {
          #pragma unroll
          for (int r = 0; r < 4; r++){
            const int tr = mt*16 + q*4 + r;
            Zoo[((size_t)b*TT + t0 + tr)*128 + (n0 - 128) + cn] = f2bf(acc[r]);
          }
        }
      }
    }
  }
  __syncthreads();

  // GEMM wdbc: 144 rows
  {
    short8 af[4][4];
    #pragma unroll
    for (int mt = 0; mt < 4; mt++)
      #pragma unroll
      for (int ks = 0; ks < 4; ks++)
        af[mt][ks] = *(const short8*)&s_xin[(mt*16 + cn)*136 + ks*32 + q*8];

    for (int nt = w; nt < 9; nt += 2){
      const int n0 = nt * 16;
      short8 bf[4];
      #pragma unroll
      for (int ks = 0; ks < 4; ks++)
        bf[ks] = *(const short8*)&wdbcb[(size_t)(n0 + cn)*128 + ks*32 + q*8];
      const int col = n0 + cn;
      #pragma unroll
      for (int mt = 0; mt < 4; mt++){
        f32x4 acc = {0.f,0.f,0.f,0.f};
        #pragma unroll
        for (int ks = 0; ks < 4; ks++) acc = MFMA(af[mt][ks], bf[ks], acc);
        if (col < 128){
          float bd = bdt[col];
          #pragma unroll
          for (int r = 0; r < 4; r++)
            DToo[((size_t)b*TT + t0 + mt*16 + q*4 + r)*128 + col] = f2bf(softplus_f(acc[r] + bd));
        } else if (col < 136){
          #pragma unroll
          for (int r = 0; r < 4; r++)
            BTo[((size_t)b*TT + t0 + mt*16 + q*4 + r)*8 + (col - 128)] = acc[r];
        } else {
          #pragma unroll
          for (int r = 0; r < 4; r++)
            CTo[((size_t)b*TT + t0 + mt*16 + q*4 + r)*8 + (col - 136)] = acc[r];
        }
      }
    }
  }
}

// ---- k_scan2h: scan(l2)+post(l2)+LNfn+head ----
__global__ __launch_bounds__(128) void k_scan2h(
    const ushort_t* DTb, const ushort_t* XINb, const ushort_t* Zb,
    const float* __restrict__ BT, const float* __restrict__ CT,
    const float* __restrict__ alog, const float* __restrict__ HST,
    const float* __restrict__ dpar, const ushort_t* __restrict__ woutb,
    float* __restrict__ X,
    const float* __restrict__ fng, const float* __restrict__ fnb,
    const ushort_t* __restrict__ pw1b, const float* __restrict__ pb1,
    const float* __restrict__ pg, const float* __restrict__ pbb,
    const ushort_t* __restrict__ pw2b, const float* __restrict__ pb2,
    float* __restrict__ out)
{
  __shared__ float4 s_bt[TSEG*2];
  __shared__ float4 s_ct[TSEG*2];
  __shared__ ushort_t s_a[64*136];
  __shared__ float s_x[64*130];
  __shared__ float s_mr[64][2];

  const int b  = blockIdx.x >> 3;
  const int sg = blockIdx.x & 7;
  const int t0 = sg * TSEG;
  const int tid = threadIdx.x;
  const int lane = tid & 63, w = tid >> 6;
  const int q = lane >> 4, cn = lane & 15;

  scan_post_ln(DTb, XINb, Zb, BT, CT, alog, HST, dpar, woutb, X,
               s_bt, s_ct, s_a, s_x, s_mr, b, sg);

  // LN_fn -> s_a bf16
  {
    float g = fng[tid], c = fnb[tid];
    for (int t = 0; t < 64; t++){
      float v = (s_x[t*130 + tid] - s_mr[t][0]) * s_mr[t][1] * g + c;
      s_a[t*136 + tid] = f2bf(v);
    }
  }
  __syncthreads();

  // pw1 GEMM -> s_x fp32 (+bias)
  {
    short8 af[4][4];
    #pragma unroll
    for (int mt = 0; mt < 4; mt++)
      #pragma unroll
      for (int ks = 0; ks < 4; ks++)
        af[mt][ks] = *(const short8*)&s_a[(mt*16 + cn)*136 + ks*32 + q*8];

    for (int nt = w; nt < 8; nt += 2){
      const int n0 = nt * 16;
      short8 bf[4];
      #pragma unroll
      for (int ks = 0; ks < 4; ks++)
        bf[ks] = *(const short8*)&pw1b[(size_t)(n0 + cn)*128 + ks*32 + q*8];
      float bias = pb1[n0 + cn];
      #pragma unroll
      for (int mt = 0; mt < 4; mt++){
        f32x4 acc = {0.f,0.f,0.f,0.f};
        #pragma unroll
        for (int ks = 0; ks < 4; ks++) acc = MFMA(af[mt][ks], bf[ks], acc);
        #pragma unroll
        for (int r = 0; r < 4; r++)
          s_x[(mt*16 + q*4 + r)*130 + n0 + cn] = acc[r] + bias;
      }
    }
  }
  __syncthreads();

  // LN stats (2 thr/token)
  {
    const int t = tid >> 1, hf = tid & 1;
    float s = 0.f, s2 = 0.f;
    const float* row = s_x + t*130 + hf*64;
    for (int j = 0; j < 64; j++){ float v = row[j]; s += v; s2 = fmaf(v, v, s2); }
    s  += __shfl_xor(s, 1, 64);
    s2 += __shfl_xor(s2, 1, 64);
    float m = s * (1.f/128.f);
    float var = s2 * (1.f/128.f) - m*m;
    if (hf == 0){ s_mr[t][0] = m; s_mr[t][1] = rsqrtf(var + 1e-5f); }
  }
  __syncthreads();
  {
    float g = pg[tid], c = pbb[tid];
    for (int t = 0; t < 64; t++){
      float v = (s_x[t*130 + tid] - s_mr[t][0]) * s_mr[t][1] * g + c;
      s_a[t*136 + tid] = f2bf(silu_f(v));
    }
  }
  __syncthreads();

  // pw2 GEMM (32 padded cols; wave w -> n-tile w)
  {
    short8 af[4][4];
    #pragma unroll
    for (int mt = 0; mt < 4; mt++)
      #pragma unroll
      for (int ks = 0; ks < 4; ks++)
        af[mt][ks] = *(const short8*)&s_a[(mt*16 + cn)*136 + ks*32 + q*8];

    const int n0 = w * 16;
    short8 bf[4];
    #pragma unroll
    for (int ks = 0; ks < 4; ks++)
      bf[ks] = *(const short8*)&pw2b[(size_t)(n0 + cn)*128 + ks*32 + q*8];
    const int col = n0 + cn;
    #pragma unroll
    for (int mt = 0; mt < 4; mt++){
      f32x4 acc = {0.f,0.f,0.f,0.f};
      #pragma unroll
      for (int ks = 0; ks < 4; ks++) acc = MFMA(af[mt][ks], bf[ks], acc);
      if (col < NAD){
        float bias = pb2[col];
        #pragma unroll
        for (int r = 0; r < 4; r++)
          out[((size_t)b*TT + t0 + mt*16 + q*4 + r)*NAD + col] = acc[r] + bias;
      }
    }
  }
}

extern "C" void kernel_launch(void* const* d_in, const int* in_sizes, int n_in,
                              void* d_out, int out_size, void* d_ws, size_t ws_size,
                              hipStream_t stream) {
  const float* obs    = (const float*)d_in[0];
  const float* h0     = (const float*)d_in[1];
  const float* enc_w1 = (const float*)d_in[2];
  const float* enc_b1 = (const float*)d_in[3];
  const float* enc_g1 = (const float*)d_in[4];
  const float* enc_bb1= (const float*)d_in[5];
  const float* enc_w2 = (const float*)d_in[6];
  const float* enc_b2 = (const float*)d_in[7];
  const float* enc_g2 = (const float*)d_in[8];
  const float* enc_bb2= (const float*)d_in[9];
  const float* emb    = (const float*)d_in[10];
  const float* proj_w = (const float*)d_in[11];
  const float* proj_b = (const float*)d_in[12];
  const float* proj_g = (const float*)d_in[13];
  const float* proj_bb= (const float*)d_in[14];
  const float* m_ln_g = (const float*)d_in[15];
  const float* m_ln_b = (const float*)d_in[16];
  const float* m_w_ig = (const float*)d_in[17];
  const float* m_w_dt = (const float*)d_in[18];
  const float* m_b_dt = (const float*)d_in[19];
  const float* m_a_log= (const float*)d_in[20];
  const float* m_w_b  = (const float*)d_in[21];
  const float* m_w_c  = (const float*)d_in[22];
  const float* m_d    = (const float*)d_in[23];
  const float* m_w_out= (const float*)d_in[24];
  const float* fn_g   = (const float*)d_in[25];
  const float* fn_b   = (const float*)d_in[26];
  const float* pol_w1 = (const float*)d_in[27];
  const float* pol_b1 = (const float*)d_in[28];
  const float* pol_g  = (const float*)d_in[29];
  const float* pol_bb = (const float*)d_in[30];
  const float* pol_w2 = (const float*)d_in[31];
  const float* pol_b2 = (const float*)d_in[32];
  const int*   pact   = (const int*)d_in[33];

  float* ws  = (float*)d_ws;
  float* X   = ws;                               // NTOK*128 fp32
  float* BT  = X  + (size_t)NTOK*128;            // NTOK*8 fp32
  float* CT  = BT + (size_t)NTOK*8;              // NTOK*8 fp32
  float* HLOC= CT + (size_t)NTOK*8;              // BB*SSEG*1024
  float* PPR = HLOC + (size_t)BB*SSEG*1024;
  float* HST = PPR  + (size_t)BB*SSEG*1024;
  ushort_t* E1   = (ushort_t*)(HST + (size_t)BB*SSEG*1024);  // NTOK*256 bf16
  ushort_t* XINb = E1   + (size_t)NTOK*256;      // NTOK*128 bf16
  ushort_t* Zb   = XINb + (size_t)NTOK*128;
  ushort_t* DTb  = Zb   + (size_t)NTOK*128;

  ushort_t* W1B   = DTb   + (size_t)NTOK*128;
  ushort_t* W2B   = W1B   + 256*128;
  ushort_t* PWB   = W2B   + 128*256;
  ushort_t* WIGB  = PWB   + 128*160;
  ushort_t* WDBCB = WIGB  + 3*256*128;
  ushort_t* WOUTB = WDBCB + 3*144*128;
  ushort_t* PW1B  = WOUTB + 3*128*128;
  ushort_t* PW2B  = PW1B  + 128*128;

  PJobs P;
  int nj = 0;
  auto add = [&](const float* src, ushort_t* dst, int N, int K, int Kpad, int rowofs, int Nw){
    P.j[nj].src = src; P.j[nj].dst = dst; P.j[nj].N = N; P.j[nj].K = K;
    P.j[nj].Kpad = Kpad; P.j[nj].rowofs = rowofs; P.j[nj].Nw = Nw; nj++;
  };
  add(enc_w1, W1B, 256, 115, 128, 0, 256);
  add(enc_w2, W2B, 128, 256, 256, 0, 128);
  add(proj_w, PWB, 128, 144, 160, 0, 128);
  for (int l = 0; l < NLD; l++)
    add(m_w_ig + (size_t)l*256*128, WIGB + (size_t)l*256*128, 256, 128, 128, 0, 256);
  for (int l = 0; l < NLD; l++){
    add(m_w_dt + (size_t)l*128*128, WDBCB + (size_t)l*144*128, 128, 128, 128, 0,   128);
    add(m_w_b  + (size_t)l*8*128,   WDBCB + (size_t)l*144*128,   8, 128, 128, 128,   8);
    add(m_w_c  + (size_t)l*8*128,   WDBCB + (size_t)l*144*128,   8, 128, 128, 136,   8);
  }
  for (int l = 0; l < NLD; l++)
    add(m_w_out + (size_t)l*128*128, WOUTB + (size_t)l*128*128, 128, 128, 128, 0, 128);
  add(pol_w1, PW1B, 128, 128, 128, 0, 128);
  add(pol_w2, PW2B,  19, 128, 128, 0,  32);

  k_prep<<<20*4, 256, 0, stream>>>(P);
  k_enc1<<<NTOK/32, 256, 0, stream>>>(obs, W1B, enc_b1, enc_g1, enc_bb1, E1);
  k_enc2p<<<NTOK/32, 256, 0, stream>>>(E1, W2B, enc_b2, enc_g2, enc_bb2,
      emb, pact, PWB, proj_b, proj_g, proj_bb, X,
      m_ln_g, m_ln_b, WIGB, WDBCB, m_b_dt,
      XINb, Zb, DTb, BT, CT);

  for (int l = 0; l < NLD; l++){
    k_scan1<<<BB*SSEG, 128, 0, stream>>>(DTb, XINb, BT,
        m_a_log + (size_t)l*DMD*DSD, HLOC, PPR);
    k_carry<<<BB, 256, 0, stream>>>(h0 + (size_t)l*BB*DMD*DSD, HLOC, PPR, HST);
    if (l < NLD-1){
      int ln = l + 1;
      k_scan2p<<<BB*SSEG, 128, 0, stream>>>(DTb, XINb, Zb, BT, CT,
          m_a_log + (size_t)l*DMD*DSD, HST, m_d + l*128,
          WOUTB + (size_t)l*128*128, X,
          m_ln_g + ln*128, m_ln_b + ln*128,
          WIGB + (size_t)ln*256*128, WDBCB + (size_t)ln*144*128, m_b_dt + ln*128,
          DTb, XINb, Zb, BT, CT);
    } else {
      k_scan2h<<<BB*SSEG, 128, 0, stream>>>(DTb, XINb, Zb, BT, CT,
          m_a_log + (size_t)l*DMD*DSD, HST, m_d + l*128,
          WOUTB + (size_t)l*128*128, X,
          fn_g, fn_b, PW1B, pol_b1, pol_g, pol_bb, PW2B, pol_b2,
          (float*)d_out);
    }
  }
}